// Round 1
// baseline (239.289 us; speedup 1.0000x reference)
//
#include <hip/hip_runtime.h>
#include <math.h>

#define CEPS 1e-8f

// Fused tower: gather F embedding fields (D=64) -> e[RT][K1] in LDS,
// h = relu(e @ W1 + b1)  (W1: [K1][256]) in LDS,
// out = relu(h @ W2 + b2) (W2: [256][128]) -> global.
// Block: 256 threads, RT=16 rows per block.
template<int F, int K1>
__global__ __launch_bounds__(256)
void tower_kernel(const int* __restrict__ ids,      // [B, F]
                  const float* __restrict__ table,  // [*, 64]
                  const float* __restrict__ W1,     // [K1, 256]
                  const float* __restrict__ b1,     // [256]
                  const float* __restrict__ W2,     // [256, 128]
                  const float* __restrict__ b2,     // [128]
                  float* __restrict__ out,          // [B, 128]
                  int B)
{
    constexpr int RT = 16;
    __shared__ float e_s[RT][K1];
    __shared__ float h_s[RT][256];
    const int row0 = blockIdx.x * RT;
    const int tid = threadIdx.x;

    // ---- gather embeddings into LDS (coalesced in d) ----
    for (int i = tid; i < RT * K1; i += 256) {
        int r = i / K1;
        int c = i - r * K1;          // c = f*64 + d
        int f = c >> 6;
        int d = c & 63;
        int row = row0 + r;
        float val = 0.f;
        if (row < B) {
            int id = ids[row * F + f];
            val = table[id * 64 + d];
        }
        e_s[r][c] = val;
    }
    __syncthreads();

    // ---- GEMM1: h[RT][256] = relu(e @ W1 + b1) ----
    {
        const int jt = tid & 63;     // col group: cols 4*jt .. 4*jt+3
        const int rg = tid >> 6;     // row group: rows 4*rg .. 4*rg+3
        float acc[4][4];
        #pragma unroll
        for (int i = 0; i < 4; ++i)
            #pragma unroll
            for (int j = 0; j < 4; ++j) acc[i][j] = 0.f;

        #pragma unroll 4
        for (int k = 0; k < K1; ++k) {
            const float4 w = *reinterpret_cast<const float4*>(&W1[k * 256 + 4 * jt]);
            #pragma unroll
            for (int i = 0; i < 4; ++i) {
                float e = e_s[4 * rg + i][k];   // wave-uniform -> LDS broadcast
                acc[i][0] += e * w.x;
                acc[i][1] += e * w.y;
                acc[i][2] += e * w.z;
                acc[i][3] += e * w.w;
            }
        }
        const float4 bb = *reinterpret_cast<const float4*>(&b1[4 * jt]);
        #pragma unroll
        for (int i = 0; i < 4; ++i) {
            float v0 = acc[i][0] + bb.x;
            float v1 = acc[i][1] + bb.y;
            float v2 = acc[i][2] + bb.z;
            float v3 = acc[i][3] + bb.w;
            h_s[4 * rg + i][4 * jt + 0] = v0 > 0.f ? v0 : 0.f;
            h_s[4 * rg + i][4 * jt + 1] = v1 > 0.f ? v1 : 0.f;
            h_s[4 * rg + i][4 * jt + 2] = v2 > 0.f ? v2 : 0.f;
            h_s[4 * rg + i][4 * jt + 3] = v3 > 0.f ? v3 : 0.f;
        }
    }
    __syncthreads();

    // ---- GEMM2: out[RT][128] = relu(h @ W2 + b2) ----
    {
        const int ct = tid & 63;     // col pair: cols 2*ct .. 2*ct+1
        const int rg = tid >> 6;     // rows 4*rg .. 4*rg+3
        float acc[4][2];
        #pragma unroll
        for (int i = 0; i < 4; ++i) { acc[i][0] = 0.f; acc[i][1] = 0.f; }

        #pragma unroll 4
        for (int k = 0; k < 256; ++k) {
            const float2 w = *reinterpret_cast<const float2*>(&W2[k * 128 + 2 * ct]);
            #pragma unroll
            for (int i = 0; i < 4; ++i) {
                float h = h_s[4 * rg + i][k];   // wave-uniform -> LDS broadcast
                acc[i][0] += h * w.x;
                acc[i][1] += h * w.y;
            }
        }
        const float2 bb = *reinterpret_cast<const float2*>(&b2[2 * ct]);
        #pragma unroll
        for (int i = 0; i < 4; ++i) {
            int row = row0 + 4 * rg + i;
            if (row < B) {
                float v0 = acc[i][0] + bb.x;
                float v1 = acc[i][1] + bb.y;
                float2 o;
                o.x = v0 > 0.f ? v0 : 0.f;
                o.y = v1 > 0.f ? v1 : 0.f;
                *reinterpret_cast<float2*>(&out[row * 128 + 2 * ct]) = o;
            }
        }
    }
}

// One wave per row: cosine similarity + sampling-bias correction.
__global__ __launch_bounds__(256)
void cosine_kernel(const float* __restrict__ U, const float* __restrict__ V,
                   const float* __restrict__ sw, float* __restrict__ y, int B)
{
    const int wave = threadIdx.x >> 6;
    const int lane = threadIdx.x & 63;
    const int r = blockIdx.x * 4 + wave;
    if (r >= B) return;
    float2 u = *reinterpret_cast<const float2*>(&U[r * 128 + 2 * lane]);
    float2 v = *reinterpret_cast<const float2*>(&V[r * 128 + 2 * lane]);
    float dot = u.x * v.x + u.y * v.y;
    float uu  = u.x * u.x + u.y * u.y;
    float vv  = v.x * v.x + v.y * v.y;
    #pragma unroll
    for (int off = 32; off; off >>= 1) {
        dot += __shfl_down(dot, off);
        uu  += __shfl_down(uu, off);
        vv  += __shfl_down(vv, off);
    }
    if (lane == 0) {
        float un = fmaxf(sqrtf(uu), CEPS);
        float vn = fmaxf(sqrtf(vv), CEPS);
        y[r] = dot / (un * vn) - logf(sw[r]);
    }
}

// scores[i][j] = y[(i+j) % B]
__global__ __launch_bounds__(256)
void scores_kernel(const float* __restrict__ y, float* __restrict__ out,
                   int B, int nn1)
{
    const int i = blockIdx.x * blockDim.x + threadIdx.x;
    if (i >= B) return;
    for (int j = 0; j < nn1; ++j) {
        int idx = i + j;
        if (idx >= B) idx -= B;
        out[i * nn1 + j] = y[idx];
    }
}

extern "C" void kernel_launch(void* const* d_in, const int* in_sizes, int n_in,
                              void* d_out, int out_size, void* d_ws, size_t ws_size,
                              hipStream_t stream)
{
    const int*   user_ids   = (const int*)  d_in[0];
    const int*   item_ids   = (const int*)  d_in[1];
    const float* sw         = (const float*)d_in[2];
    const float* user_table = (const float*)d_in[3];
    const float* item_table = (const float*)d_in[4];
    const float* uW1        = (const float*)d_in[5];
    const float* ub1        = (const float*)d_in[6];
    const float* uW2        = (const float*)d_in[7];
    const float* ub2        = (const float*)d_in[8];
    const float* iW1        = (const float*)d_in[9];
    const float* ib1        = (const float*)d_in[10];
    const float* iW2        = (const float*)d_in[11];
    const float* ib2        = (const float*)d_in[12];

    const int B   = in_sizes[2];        // sample_weight length
    const int nn1 = out_size / B;       // n_neg + 1

    float* U = (float*)d_ws;                    // [B,128]
    float* V = U + (size_t)B * 128;             // [B,128]
    float* y = V + (size_t)B * 128;             // [B]
    float* out = (float*)d_out;

    const int nblk = (B + 15) / 16;
    tower_kernel<8, 512><<<nblk, 256, 0, stream>>>(user_ids, user_table,
                                                   uW1, ub1, uW2, ub2, U, B);
    tower_kernel<4, 256><<<nblk, 256, 0, stream>>>(item_ids, item_table,
                                                   iW1, ib1, iW2, ib2, V, B);
    cosine_kernel<<<(B + 3) / 4, 256, 0, stream>>>(U, V, sw, y, B);
    scores_kernel<<<(B + 255) / 256, 256, 0, stream>>>(y, out, B, nn1);
}

// Round 2
// 49.425 us; speedup vs baseline: 4.8414x; 4.8414x over previous
//
#include <hip/hip_runtime.h>
#include <math.h>

#define CEPS 1e-8f

typedef __attribute__((ext_vector_type(8))) short bf16x8;
typedef __attribute__((ext_vector_type(4))) float f32x4;
typedef __attribute__((ext_vector_type(4))) unsigned int u32x4;

__device__ __forceinline__ unsigned short f2bf(float f) {
    unsigned u = __builtin_bit_cast(unsigned, f);
    u += 0x7fffu + ((u >> 16) & 1u);            // round-nearest-even
    return (unsigned short)(u >> 16);
}

// Pack all 4 weight matrices fp32 -> bf16 in MFMA-B layout [K/8][N][8]
// (lane's 8 K-contiguous elements land in one contiguous 16B chunk).
__global__ __launch_bounds__(256)
void pack_all(const float* __restrict__ uW1, const float* __restrict__ uW2,
              const float* __restrict__ iW1, const float* __restrict__ iW2,
              unsigned short* __restrict__ o1, unsigned short* __restrict__ o2,
              unsigned short* __restrict__ o3, unsigned short* __restrict__ o4)
{
    int g = blockIdx.x * 256 + threadIdx.x;     // 262144 total
    const float* src; unsigned short* dst; int N; int base;
    if (g < 131072)      { src = uW1; dst = o1; N = 256; base = 0;      }
    else if (g < 163840) { src = uW2; dst = o2; N = 128; base = 131072; }
    else if (g < 229376) { src = iW1; dst = o3; N = 256; base = 163840; }
    else                 { src = iW2; dst = o4; N = 128; base = 229376; }
    int i = g - base;
    int k = i / N, n = i - k * N;
    dst[(((k >> 3) * N + n) << 3) + (k & 7)] = f2bf(src[i]);
}

// Fused tower: gather -> bf16 LDS (XOR-swizzled) -> MFMA GEMM1 -> relu ->
// bf16 LDS -> MFMA GEMM2 -> relu -> fp32 out.  32 rows/block, 4 waves.
template<int F, int K1>
__global__ __launch_bounds__(256)
void tower_mfma(const int* __restrict__ ids,            // [B,F]
                const float* __restrict__ table,        // [*,64]
                const unsigned short* __restrict__ W1p, // [K1/8][256][8]
                const float* __restrict__ b1,           // [256]
                const unsigned short* __restrict__ W2p, // [256/8][128][8]
                const float* __restrict__ b2,           // [128]
                float* __restrict__ out)                // [B,128]
{
    constexpr int RT = 32, N1 = 256, K2 = 256;
    __shared__ unsigned short e_s[RT * K1];
    __shared__ unsigned short h_s[RT * K2];
    const int tid  = threadIdx.x;
    const int lane = tid & 63;
    const int w    = tid >> 6;
    const int row0 = blockIdx.x * RT;

    // ---- gather embeddings -> swizzled bf16 LDS ----
    constexpr int FC = F * 8;                    // 16B chunks per row
    for (int c = tid; c < RT * FC; c += 256) {
        int r = c / FC, rem = c % FC;
        int f = rem >> 3, ci = rem & 7;
        int id = ids[(row0 + r) * F + f];
        const float* src = table + (size_t)id * 64 + ci * 8;
        float4 aa = *reinterpret_cast<const float4*>(src);
        float4 bb = *reinterpret_cast<const float4*>(src + 4);
        u32x4 pk;
        pk.x = f2bf(aa.x) | ((unsigned)f2bf(aa.y) << 16);
        pk.y = f2bf(aa.z) | ((unsigned)f2bf(aa.w) << 16);
        pk.z = f2bf(bb.x) | ((unsigned)f2bf(bb.y) << 16);
        pk.w = f2bf(bb.z) | ((unsigned)f2bf(bb.w) << 16);
        int byte = r * (K1 * 2) + (f * 64 + ci * 8) * 2;
        byte ^= (r & 7) << 4;
        *reinterpret_cast<u32x4*>(reinterpret_cast<char*>(e_s) + byte) = pk;
    }
    __syncthreads();

    // ---- GEMM1: h[32][256] = relu(e @ W1 + b1) ----
    f32x4 acc1[2][4];
    #pragma unroll
    for (int m = 0; m < 2; ++m)
        #pragma unroll
        for (int n = 0; n < 4; ++n) acc1[m][n] = (f32x4){0.f, 0.f, 0.f, 0.f};

    const int colbase1 = w * 64;
    #pragma unroll 2
    for (int ks = 0; ks < K1 / 32; ++ks) {
        bf16x8 a[2];
        #pragma unroll
        for (int m = 0; m < 2; ++m) {
            int row = m * 16 + (lane & 15);
            int byte = row * (K1 * 2) + (ks * 32 + (lane >> 4) * 8) * 2;
            byte ^= (row & 7) << 4;
            a[m] = *reinterpret_cast<const bf16x8*>(
                       reinterpret_cast<const char*>(e_s) + byte);
        }
        #pragma unroll
        for (int n = 0; n < 4; ++n) {
            int col = colbase1 + n * 16 + (lane & 15);
            int kg  = ks * 4 + (lane >> 4);
            bf16x8 bf = *reinterpret_cast<const bf16x8*>(W1p + ((kg * N1 + col) << 3));
            #pragma unroll
            for (int m = 0; m < 2; ++m)
                acc1[m][n] = __builtin_amdgcn_mfma_f32_16x16x32_bf16(
                                 a[m], bf, acc1[m][n], 0, 0, 0);
        }
    }
    // epilogue 1: +bias, relu, bf16 -> swizzled h_s
    #pragma unroll
    for (int n = 0; n < 4; ++n) {
        int col = colbase1 + n * 16 + (lane & 15);
        float bias = b1[col];
        #pragma unroll
        for (int m = 0; m < 2; ++m)
            #pragma unroll
            for (int r = 0; r < 4; ++r) {
                int row = m * 16 + (lane >> 4) * 4 + r;
                float v = acc1[m][n][r] + bias;
                v = v > 0.f ? v : 0.f;
                int byte = (row * K2 + col) * 2;
                byte ^= (row & 7) << 4;
                *reinterpret_cast<unsigned short*>(
                    reinterpret_cast<char*>(h_s) + byte) = f2bf(v);
            }
    }
    __syncthreads();

    // ---- GEMM2: out[32][128] = relu(h @ W2 + b2) ----
    f32x4 acc2[2][2];
    #pragma unroll
    for (int m = 0; m < 2; ++m)
        #pragma unroll
        for (int n = 0; n < 2; ++n) acc2[m][n] = (f32x4){0.f, 0.f, 0.f, 0.f};

    const int colbase2 = w * 32;
    #pragma unroll 2
    for (int ks = 0; ks < K2 / 32; ++ks) {
        bf16x8 a[2];
        #pragma unroll
        for (int m = 0; m < 2; ++m) {
            int row = m * 16 + (lane & 15);
            int byte = row * (K2 * 2) + (ks * 32 + (lane >> 4) * 8) * 2;
            byte ^= (row & 7) << 4;
            a[m] = *reinterpret_cast<const bf16x8*>(
                       reinterpret_cast<const char*>(h_s) + byte);
        }
        #pragma unroll
        for (int n = 0; n < 2; ++n) {
            int col = colbase2 + n * 16 + (lane & 15);
            int kg  = ks * 4 + (lane >> 4);
            bf16x8 bf = *reinterpret_cast<const bf16x8*>(W2p + ((kg * 128 + col) << 3));
            #pragma unroll
            for (int m = 0; m < 2; ++m)
                acc2[m][n] = __builtin_amdgcn_mfma_f32_16x16x32_bf16(
                                 a[m], bf, acc2[m][n], 0, 0, 0);
        }
    }
    // epilogue 2: +bias, relu -> global fp32
    #pragma unroll
    for (int n = 0; n < 2; ++n) {
        int col = colbase2 + n * 16 + (lane & 15);
        float bias = b2[col];
        #pragma unroll
        for (int m = 0; m < 2; ++m)
            #pragma unroll
            for (int r = 0; r < 4; ++r) {
                int row = row0 + m * 16 + (lane >> 4) * 4 + r;
                float v = acc2[m][n][r] + bias;
                out[row * 128 + col] = v > 0.f ? v : 0.f;
            }
    }
}

// One wave per row: cosine similarity + sampling-bias correction.
__global__ __launch_bounds__(256)
void cosine_kernel(const float* __restrict__ U, const float* __restrict__ V,
                   const float* __restrict__ sw, float* __restrict__ y, int B)
{
    const int wave = threadIdx.x >> 6;
    const int lane = threadIdx.x & 63;
    const int r = blockIdx.x * 4 + wave;
    if (r >= B) return;
    float2 u = *reinterpret_cast<const float2*>(&U[r * 128 + 2 * lane]);
    float2 v = *reinterpret_cast<const float2*>(&V[r * 128 + 2 * lane]);
    float dot = u.x * v.x + u.y * v.y;
    float uu  = u.x * u.x + u.y * u.y;
    float vv  = v.x * v.x + v.y * v.y;
    #pragma unroll
    for (int off = 32; off; off >>= 1) {
        dot += __shfl_down(dot, off);
        uu  += __shfl_down(uu, off);
        vv  += __shfl_down(vv, off);
    }
    if (lane == 0) {
        float un = fmaxf(sqrtf(uu), CEPS);
        float vn = fmaxf(sqrtf(vv), CEPS);
        y[r] = dot / (un * vn) - logf(sw[r]);
    }
}

// scores[i][j] = y[(i+j) % B]
__global__ __launch_bounds__(256)
void scores_kernel(const float* __restrict__ y, float* __restrict__ out,
                   int B, int nn1)
{
    const int i = blockIdx.x * blockDim.x + threadIdx.x;
    if (i >= B) return;
    for (int j = 0; j < nn1; ++j) {
        int idx = i + j;
        if (idx >= B) idx -= B;
        out[i * nn1 + j] = y[idx];
    }
}

extern "C" void kernel_launch(void* const* d_in, const int* in_sizes, int n_in,
                              void* d_out, int out_size, void* d_ws, size_t ws_size,
                              hipStream_t stream)
{
    const int*   user_ids   = (const int*)  d_in[0];
    const int*   item_ids   = (const int*)  d_in[1];
    const float* sw         = (const float*)d_in[2];
    const float* user_table = (const float*)d_in[3];
    const float* item_table = (const float*)d_in[4];
    const float* uW1        = (const float*)d_in[5];
    const float* ub1        = (const float*)d_in[6];
    const float* uW2        = (const float*)d_in[7];
    const float* ub2        = (const float*)d_in[8];
    const float* iW1        = (const float*)d_in[9];
    const float* ib1        = (const float*)d_in[10];
    const float* iW2        = (const float*)d_in[11];
    const float* ib2        = (const float*)d_in[12];

    const int B   = in_sizes[2];       // 16384
    const int nn1 = out_size / B;      // n_neg + 1

    unsigned short* wp   = (unsigned short*)d_ws;
    unsigned short* uW1p = wp;               // 131072
    unsigned short* uW2p = wp + 131072;      // 32768
    unsigned short* iW1p = wp + 163840;      // 65536
    unsigned short* iW2p = wp + 229376;      // 32768
    float* U = (float*)(wp + 262144);        // [B,128]
    float* V = U + (size_t)B * 128;          // [B,128]
    float* y = V + (size_t)B * 128;          // [B]
    float* out = (float*)d_out;

    pack_all<<<1024, 256, 0, stream>>>(uW1, uW2, iW1, iW2,
                                       uW1p, uW2p, iW1p, iW2p);
    tower_mfma<8, 512><<<B / 32, 256, 0, stream>>>(user_ids, user_table,
                                                   uW1p, ub1, uW2p, ub2, U);
    tower_mfma<4, 256><<<B / 32, 256, 0, stream>>>(item_ids, item_table,
                                                   iW1p, ib1, iW2p, ib2, V);
    cosine_kernel<<<(B + 3) / 4, 256, 0, stream>>>(U, V, sw, y, B);
    scores_kernel<<<(B + 255) / 256, 256, 0, stream>>>(y, out, B, nn1);
}

// Round 3
// 39.002 us; speedup vs baseline: 6.1353x; 1.2672x over previous
//
#include <hip/hip_runtime.h>
#include <math.h>

#define CEPS 1e-8f

typedef __attribute__((ext_vector_type(8))) short bf16x8;
typedef __attribute__((ext_vector_type(4))) float f32x4;
typedef __attribute__((ext_vector_type(4))) unsigned int u32x4;

__device__ __forceinline__ unsigned short f2bf(float f) {
    unsigned u = __builtin_bit_cast(unsigned, f);
    u += 0x7fffu + ((u >> 16) & 1u);            // round-nearest-even
    return (unsigned short)(u >> 16);
}

// Pack all 4 weight matrices fp32 -> bf16 in MFMA-B layout [K/8][N][8].
__global__ __launch_bounds__(256)
void pack_all(const float* __restrict__ uW1, const float* __restrict__ uW2,
              const float* __restrict__ iW1, const float* __restrict__ iW2,
              unsigned short* __restrict__ o1, unsigned short* __restrict__ o2,
              unsigned short* __restrict__ o3, unsigned short* __restrict__ o4)
{
    int g = blockIdx.x * 256 + threadIdx.x;     // 262144 total
    const float* src; unsigned short* dst; int N; int base;
    if (g < 131072)      { src = uW1; dst = o1; N = 256; base = 0;      }
    else if (g < 163840) { src = uW2; dst = o2; N = 128; base = 131072; }
    else if (g < 229376) { src = iW1; dst = o3; N = 256; base = 163840; }
    else                 { src = iW2; dst = o4; N = 128; base = 229376; }
    int i = g - base;
    int k = i / N, n = i - k * N;
    dst[(((k >> 3) * N + n) << 3) + (k & 7)] = f2bf(src[i]);
}

// ---------------- fused towers + cosine + score scatter ----------------
// 32 rows/block, 256 threads (4 waves, each owns 32 of the 128 output dims).

__device__ __forceinline__ void stage_emb(
    const int* __restrict__ ids, const float* __restrict__ table,
    unsigned short* e_s, int row0, int F, int Kstride, int tid)
{
    const int FC = F * 8;                        // 16B chunks per row
    for (int c = tid; c < 32 * FC; c += 256) {
        int r = c / FC, rem = c % FC;
        int f = rem >> 3, ci = rem & 7;
        int id = ids[(row0 + r) * F + f];
        const float* src = table + (size_t)id * 64 + ci * 8;
        float4 aa = *reinterpret_cast<const float4*>(src);
        float4 bb = *reinterpret_cast<const float4*>(src + 4);
        u32x4 pk;
        pk.x = f2bf(aa.x) | ((unsigned)f2bf(aa.y) << 16);
        pk.y = f2bf(aa.z) | ((unsigned)f2bf(aa.w) << 16);
        pk.z = f2bf(bb.x) | ((unsigned)f2bf(bb.y) << 16);
        pk.w = f2bf(bb.z) | ((unsigned)f2bf(bb.w) << 16);
        int byte = r * (Kstride * 2) + (f * 64 + ci * 8) * 2;
        byte ^= (r & 7) << 4;
        *reinterpret_cast<u32x4*>(reinterpret_cast<char*>(e_s) + byte) = pk;
    }
}

// GEMM1: h[32][256] = relu(e[32][K1] @ W1 + b1), e swizzled in LDS.
template<int K1>
__device__ __forceinline__ void gemm1(
    const unsigned short* e_s, unsigned short* h_s,
    const unsigned short* __restrict__ W1p, const float* __restrict__ b1,
    int lane, int w)
{
    f32x4 acc[2][4];
    #pragma unroll
    for (int m = 0; m < 2; ++m)
        #pragma unroll
        for (int n = 0; n < 4; ++n) acc[m][n] = (f32x4){0.f, 0.f, 0.f, 0.f};

    const int colbase = w * 64;
    #pragma unroll 2
    for (int ks = 0; ks < K1 / 32; ++ks) {
        bf16x8 a[2];
        #pragma unroll
        for (int m = 0; m < 2; ++m) {
            int row = m * 16 + (lane & 15);
            int byte = row * (K1 * 2) + (ks * 32 + (lane >> 4) * 8) * 2;
            byte ^= (row & 7) << 4;
            a[m] = *reinterpret_cast<const bf16x8*>(
                       reinterpret_cast<const char*>(e_s) + byte);
        }
        #pragma unroll
        for (int n = 0; n < 4; ++n) {
            int col = colbase + n * 16 + (lane & 15);
            int kg  = ks * 4 + (lane >> 4);
            bf16x8 bf = *reinterpret_cast<const bf16x8*>(W1p + ((kg * 256 + col) << 3));
            #pragma unroll
            for (int m = 0; m < 2; ++m)
                acc[m][n] = __builtin_amdgcn_mfma_f32_16x16x32_bf16(
                                a[m], bf, acc[m][n], 0, 0, 0);
        }
    }
    #pragma unroll
    for (int n = 0; n < 4; ++n) {
        int col = colbase + n * 16 + (lane & 15);
        float bias = b1[col];
        #pragma unroll
        for (int m = 0; m < 2; ++m)
            #pragma unroll
            for (int r = 0; r < 4; ++r) {
                int row = m * 16 + (lane >> 4) * 4 + r;
                float v = acc[m][n][r] + bias;
                v = v > 0.f ? v : 0.f;
                int byte = (row * 256 + col) * 2;
                byte ^= (row & 7) << 4;
                *reinterpret_cast<unsigned short*>(
                    reinterpret_cast<char*>(h_s) + byte) = f2bf(v);
            }
    }
}

// GEMM2: acc[2][2] += h[32][256] @ W2 (cols w*32..w*32+31), no epilogue.
__device__ __forceinline__ void gemm2(
    const unsigned short* h_s, const unsigned short* __restrict__ W2p,
    f32x4 (&acc)[2][2], int lane, int w)
{
    #pragma unroll
    for (int m = 0; m < 2; ++m)
        #pragma unroll
        for (int n = 0; n < 2; ++n) acc[m][n] = (f32x4){0.f, 0.f, 0.f, 0.f};
    const int colbase = w * 32;
    #pragma unroll 2
    for (int ks = 0; ks < 8; ++ks) {
        bf16x8 a[2];
        #pragma unroll
        for (int m = 0; m < 2; ++m) {
            int row = m * 16 + (lane & 15);
            int byte = row * (256 * 2) + (ks * 32 + (lane >> 4) * 8) * 2;
            byte ^= (row & 7) << 4;
            a[m] = *reinterpret_cast<const bf16x8*>(
                       reinterpret_cast<const char*>(h_s) + byte);
        }
        #pragma unroll
        for (int n = 0; n < 2; ++n) {
            int col = colbase + n * 16 + (lane & 15);
            int kg  = ks * 4 + (lane >> 4);
            bf16x8 bf = *reinterpret_cast<const bf16x8*>(W2p + ((kg * 128 + col) << 3));
            #pragma unroll
            for (int m = 0; m < 2; ++m)
                acc[m][n] = __builtin_amdgcn_mfma_f32_16x16x32_bf16(
                                a[m], bf, acc[m][n], 0, 0, 0);
        }
    }
}

__global__ __launch_bounds__(256)
void fused_sbc(const int* __restrict__ user_ids,  const int* __restrict__ item_ids,
               const float* __restrict__ user_table, const float* __restrict__ item_table,
               const unsigned short* __restrict__ uW1p, const float* __restrict__ ub1,
               const unsigned short* __restrict__ uW2p, const float* __restrict__ ub2,
               const unsigned short* __restrict__ iW1p, const float* __restrict__ ib1,
               const unsigned short* __restrict__ iW2p, const float* __restrict__ ib2,
               const float* __restrict__ sw, float* __restrict__ out,
               int B, int nn1)
{
    __shared__ unsigned short e_s[32 * 512];
    __shared__ unsigned short h_s[32 * 256];
    __shared__ float red[4][32][3];

    const int tid  = threadIdx.x;
    const int lane = tid & 63;
    const int w    = tid >> 6;
    const int row0 = blockIdx.x * 32;

    // ---- user tower ----
    stage_emb(user_ids, user_table, e_s, row0, 8, 512, tid);
    __syncthreads();
    gemm1<512>(e_s, h_s, uW1p, ub1, lane, w);
    __syncthreads();                       // h_s ready; e_s reads done
    stage_emb(item_ids, item_table, e_s, row0, 4, 256, tid);   // overlap w/ GEMM2
    f32x4 accU[2][2];
    gemm2(h_s, uW2p, accU, lane, w);
    __syncthreads();                       // item e_s ready; h_s reads done

    // ---- item tower ----
    gemm1<256>(e_s, h_s, iW1p, ib1, lane, w);
    __syncthreads();
    f32x4 accV[2][2];
    gemm2(h_s, iW2p, accV, lane, w);

    // ---- bias + relu + cosine partials ----
    float bu[2], bv[2];
    #pragma unroll
    for (int n = 0; n < 2; ++n) {
        int col = w * 32 + n * 16 + (lane & 15);
        bu[n] = ub2[col];
        bv[n] = ib2[col];
    }
    float pd[8], pu[8], pv[8];
    #pragma unroll
    for (int m = 0; m < 2; ++m)
        #pragma unroll
        for (int r = 0; r < 4; ++r) {
            float d = 0.f, su = 0.f, sv = 0.f;
            #pragma unroll
            for (int n = 0; n < 2; ++n) {
                float uval = accU[m][n][r] + bu[n];
                float vval = accV[m][n][r] + bv[n];
                uval = uval > 0.f ? uval : 0.f;
                vval = vval > 0.f ? vval : 0.f;
                d  += uval * vval;
                su += uval * uval;
                sv += vval * vval;
            }
            int i = m * 4 + r;
            pd[i] = d; pu[i] = su; pv[i] = sv;
        }
    // reduce across the 16 lanes sharing (lane>>4)
    #pragma unroll
    for (int off = 1; off < 16; off <<= 1) {
        #pragma unroll
        for (int i = 0; i < 8; ++i) {
            pd[i] += __shfl_xor(pd[i], off);
            pu[i] += __shfl_xor(pu[i], off);
            pv[i] += __shfl_xor(pv[i], off);
        }
    }
    if ((lane & 15) == 0) {
        int q = lane >> 4;
        #pragma unroll
        for (int m = 0; m < 2; ++m)
            #pragma unroll
            for (int r = 0; r < 4; ++r) {
                int row = m * 16 + q * 4 + r;
                int i = m * 4 + r;
                red[w][row][0] = pd[i];
                red[w][row][1] = pu[i];
                red[w][row][2] = pv[i];
            }
    }
    __syncthreads();

    // ---- final reduce + y + scatter ----
    if (tid < 32) {
        int row = tid;
        float d = 0.f, su = 0.f, sv = 0.f;
        #pragma unroll
        for (int ww = 0; ww < 4; ++ww) {
            d  += red[ww][row][0];
            su += red[ww][row][1];
            sv += red[ww][row][2];
        }
        float un = fmaxf(sqrtf(su), CEPS);
        float vn = fmaxf(sqrtf(sv), CEPS);
        int grow = row0 + row;
        float yv = d / (un * vn) - logf(sw[grow]);
        for (int j = 0; j < nn1; ++j) {
            int idx = grow - j;
            if (idx < 0) idx += B;
            out[idx * nn1 + j] = yv;
        }
    }
}

extern "C" void kernel_launch(void* const* d_in, const int* in_sizes, int n_in,
                              void* d_out, int out_size, void* d_ws, size_t ws_size,
                              hipStream_t stream)
{
    const int*   user_ids   = (const int*)  d_in[0];
    const int*   item_ids   = (const int*)  d_in[1];
    const float* sw         = (const float*)d_in[2];
    const float* user_table = (const float*)d_in[3];
    const float* item_table = (const float*)d_in[4];
    const float* uW1        = (const float*)d_in[5];
    const float* ub1        = (const float*)d_in[6];
    const float* uW2        = (const float*)d_in[7];
    const float* ub2        = (const float*)d_in[8];
    const float* iW1        = (const float*)d_in[9];
    const float* ib1        = (const float*)d_in[10];
    const float* iW2        = (const float*)d_in[11];
    const float* ib2        = (const float*)d_in[12];

    const int B   = in_sizes[2];       // 16384
    const int nn1 = out_size / B;      // n_neg + 1

    unsigned short* wp   = (unsigned short*)d_ws;
    unsigned short* uW1p = wp;               // 131072
    unsigned short* uW2p = wp + 131072;      // 32768
    unsigned short* iW1p = wp + 163840;      // 65536
    unsigned short* iW2p = wp + 229376;      // 32768
    float* out = (float*)d_out;

    pack_all<<<1024, 256, 0, stream>>>(uW1, uW2, iW1, iW2,
                                       uW1p, uW2p, iW1p, iW2p);
    fused_sbc<<<B / 32, 256, 0, stream>>>(user_ids, item_ids,
                                          user_table, item_table,
                                          uW1p, ub1, uW2p, ub2,
                                          iW1p, ib1, iW2p, ib2,
                                          sw, out, B, nn1);
}

// Round 4
// 33.955 us; speedup vs baseline: 7.0473x; 1.1487x over previous
//
#include <hip/hip_runtime.h>
#include <math.h>

#define CEPS 1e-8f

typedef __attribute__((ext_vector_type(8))) short bf16x8;
typedef __attribute__((ext_vector_type(4))) float f32x4;
typedef __attribute__((ext_vector_type(4))) unsigned int u32x4;

__device__ __forceinline__ unsigned short f2bf(float f) {
    unsigned u = __builtin_bit_cast(unsigned, f);
    u += 0x7fffu + ((u >> 16) & 1u);            // round-nearest-even
    return (unsigned short)(u >> 16);
}

// Pack weights fp32 -> bf16, MFMA-B layout [K/8][N][8].
// One thread per (kg,n) entry: 8 coalesced row reads, one bf16x8 store.
__global__ __launch_bounds__(256)
void pack_all(const float* __restrict__ uW1, const float* __restrict__ uW2,
              const float* __restrict__ iW1, const float* __restrict__ iW2,
              unsigned short* __restrict__ o1, unsigned short* __restrict__ o2,
              unsigned short* __restrict__ o3, unsigned short* __restrict__ o4)
{
    int g = blockIdx.x * 256 + threadIdx.x;     // 32768 entries
    const float* src; unsigned short* dst; int N; int base;
    if (g < 16384)      { src = uW1; dst = o1; N = 256; base = 0;     }
    else if (g < 20480) { src = uW2; dst = o2; N = 128; base = 16384; }
    else if (g < 28672) { src = iW1; dst = o3; N = 256; base = 20480; }
    else                { src = iW2; dst = o4; N = 128; base = 28672; }
    int i = g - base;
    int kg = i / N, n = i - kg * N;
    unsigned short tmp[8];
    #pragma unroll
    for (int j = 0; j < 8; ++j)
        tmp[j] = f2bf(src[(kg * 8 + j) * N + n]);
    *reinterpret_cast<bf16x8*>(dst + ((size_t)i << 3)) =
        *reinterpret_cast<bf16x8*>(tmp);
}

// ---------------- fused towers + cosine + score scatter ----------------
// 32 rows/block, 512 threads (8 waves, each owns 16..32 of the output dims).

// gather -> bf16, XOR-swizzled LDS.  512 threads, F/2 iterations each.
template<int F>
__device__ __forceinline__ void stage_emb(const int* __restrict__ ids,
                                          const float* __restrict__ table,
                                          unsigned short* e_s, int row0, int tid)
{
    constexpr int FC = F * 8;                    // 16B chunks per row
    constexpr int IT = F / 2;                    // (32*FC)/512
    int idv[IT];
    #pragma unroll
    for (int it = 0; it < IT; ++it) {
        int c = tid + it * 512;
        int r = c / FC, f = (c % FC) >> 3;
        idv[it] = ids[(row0 + r) * F + f];
    }
    #pragma unroll
    for (int it = 0; it < IT; ++it) {
        int c = tid + it * 512;
        int r = c / FC, rem = c % FC, ci = rem & 7;
        const float* src = table + (size_t)idv[it] * 64 + ci * 8;
        float4 aa = *reinterpret_cast<const float4*>(src);
        float4 bb = *reinterpret_cast<const float4*>(src + 4);
        u32x4 pk;
        pk.x = f2bf(aa.x) | ((unsigned)f2bf(aa.y) << 16);
        pk.y = f2bf(aa.z) | ((unsigned)f2bf(aa.w) << 16);
        pk.z = f2bf(bb.x) | ((unsigned)f2bf(bb.y) << 16);
        pk.w = f2bf(bb.z) | ((unsigned)f2bf(bb.w) << 16);
        int byte = r * (F * 128) + rem * 16;
        byte ^= (r & 7) << 4;
        *reinterpret_cast<u32x4*>(reinterpret_cast<char*>(e_s) + byte) = pk;
    }
}

template<int K1>
__device__ __forceinline__ bf16x8 loadA(const unsigned short* e_s, int ks, int m,
                                        int l15, int l4)
{
    int row = m * 16 + l15;
    int byte = row * (K1 * 2) + ks * 64 + l4 * 16;
    byte ^= (row & 7) << 4;
    return *reinterpret_cast<const bf16x8*>(
               reinterpret_cast<const char*>(e_s) + byte);
}

template<int NFRAG>
__device__ __forceinline__ void preloadB(const unsigned short* __restrict__ Wp,
                                         int N, int colbase, int lane, bf16x8* b0)
{
    const unsigned short* base =
        Wp + ((((lane >> 4) * N) + colbase + (lane & 15)) << 3);
    #pragma unroll
    for (int n = 0; n < NFRAG; ++n)
        b0[n] = *reinterpret_cast<const bf16x8*>(base + (n << 7));
}

// GEMM1: h[32][256] = relu(e[32][K1] @ W1 + b1).  Per wave: 2 n-frags (32 cols).
template<int K1>
__device__ __forceinline__ void gemm1(
    const unsigned short* e_s, unsigned short* h_s,
    const unsigned short* __restrict__ W1p, const float* __restrict__ b1,
    int lane, int w, const bf16x8* b0)
{
    constexpr int NKS = K1 / 32;
    const int l15 = lane & 15, l4 = lane >> 4;
    const int colbase = w * 32;
    f32x4 acc[2][2];
    #pragma unroll
    for (int m = 0; m < 2; ++m)
        #pragma unroll
        for (int n = 0; n < 2; ++n) acc[m][n] = (f32x4){0.f, 0.f, 0.f, 0.f};

    const unsigned short* Wbase = W1p + (((l4 * 256) + colbase + l15) << 3);
    bf16x8 aB[2][2], bB[2][2];
    bB[0][0] = b0[0];
    bB[0][1] = b0[1];
    #pragma unroll
    for (int m = 0; m < 2; ++m) aB[0][m] = loadA<K1>(e_s, 0, m, l15, l4);

    #pragma unroll
    for (int ks = 0; ks < NKS; ++ks) {
        const int cur = ks & 1, nxt = cur ^ 1;
        if (ks + 1 < NKS) {
            #pragma unroll
            for (int m = 0; m < 2; ++m)
                aB[nxt][m] = loadA<K1>(e_s, ks + 1, m, l15, l4);
            #pragma unroll
            for (int n = 0; n < 2; ++n)
                bB[nxt][n] = *reinterpret_cast<const bf16x8*>(
                                 Wbase + (ks + 1) * 8192 + (n << 7));
        }
        #pragma unroll
        for (int n = 0; n < 2; ++n)
            #pragma unroll
            for (int m = 0; m < 2; ++m)
                acc[m][n] = __builtin_amdgcn_mfma_f32_16x16x32_bf16(
                                aB[cur][m], bB[cur][n], acc[m][n], 0, 0, 0);
    }
    #pragma unroll
    for (int n = 0; n < 2; ++n) {
        int col = colbase + n * 16 + l15;
        float bias = b1[col];
        #pragma unroll
        for (int m = 0; m < 2; ++m)
            #pragma unroll
            for (int r = 0; r < 4; ++r) {
                int row = m * 16 + l4 * 4 + r;
                float v = acc[m][n][r] + bias;
                v = v > 0.f ? v : 0.f;
                int byte = (row * 256 + col) * 2;
                byte ^= (row & 7) << 4;
                *reinterpret_cast<unsigned short*>(
                    reinterpret_cast<char*>(h_s) + byte) = f2bf(v);
            }
    }
}

// GEMM2: acc[2] += h[32][256] @ W2 (cols w*16..w*16+15), no epilogue.
__device__ __forceinline__ void gemm2(
    const unsigned short* h_s, const unsigned short* __restrict__ W2p,
    f32x4 (&acc)[2], int lane, int w, bf16x8 b0)
{
    const int l15 = lane & 15, l4 = lane >> 4;
    const int col = w * 16 + l15;
    #pragma unroll
    for (int m = 0; m < 2; ++m) acc[m] = (f32x4){0.f, 0.f, 0.f, 0.f};

    const unsigned short* Wbase = W2p + (((l4 * 128) + col) << 3);
    bf16x8 aB[2][2], bB[2];
    bB[0] = b0;
    #pragma unroll
    for (int m = 0; m < 2; ++m) aB[0][m] = loadA<256>(h_s, 0, m, l15, l4);

    #pragma unroll
    for (int ks = 0; ks < 8; ++ks) {
        const int cur = ks & 1, nxt = cur ^ 1;
        if (ks + 1 < 8) {
            #pragma unroll
            for (int m = 0; m < 2; ++m)
                aB[nxt][m] = loadA<256>(h_s, ks + 1, m, l15, l4);
            bB[nxt] = *reinterpret_cast<const bf16x8*>(Wbase + (ks + 1) * 4096);
        }
        #pragma unroll
        for (int m = 0; m < 2; ++m)
            acc[m] = __builtin_amdgcn_mfma_f32_16x16x32_bf16(
                         aB[cur][m], bB[cur], acc[m], 0, 0, 0);
    }
}

__global__ __launch_bounds__(512, 4)
void fused_sbc(const int* __restrict__ user_ids,  const int* __restrict__ item_ids,
               const float* __restrict__ user_table, const float* __restrict__ item_table,
               const unsigned short* __restrict__ uW1p, const float* __restrict__ ub1,
               const unsigned short* __restrict__ uW2p, const float* __restrict__ ub2,
               const unsigned short* __restrict__ iW1p, const float* __restrict__ ib1,
               const unsigned short* __restrict__ iW2p, const float* __restrict__ ib2,
               const float* __restrict__ sw, float* __restrict__ out,
               int B, int nn1)
{
    __shared__ unsigned short e_s[32 * 512];
    __shared__ unsigned short h_s[32 * 256];
    __shared__ float red[8][32][3];

    const int tid  = threadIdx.x;
    const int lane = tid & 63;
    const int w    = tid >> 6;
    const int row0 = blockIdx.x * 32;

    // ---- user tower ----
    bf16x8 b0u1[2];
    preloadB<2>(uW1p, 256, w * 32, lane, b0u1);     // in flight over staging+barrier
    stage_emb<8>(user_ids, user_table, e_s, row0, tid);
    __syncthreads();

    gemm1<512>(e_s, h_s, uW1p, ub1, lane, w, b0u1);
    bf16x8 b0u2[1], b0i1[2];
    preloadB<1>(uW2p, 128, w * 16, lane, b0u2);     // in flight over barrier
    preloadB<2>(iW1p, 256, w * 32, lane, b0i1);
    __syncthreads();                       // h_s ready; e_s reads done

    stage_emb<4>(item_ids, item_table, e_s, row0, tid);  // overlap w/ GEMM2
    f32x4 accU[2];
    gemm2(h_s, uW2p, accU, lane, w, b0u2[0]);
    __syncthreads();                       // item e_s ready; h_s reads done

    // ---- item tower ----
    gemm1<256>(e_s, h_s, iW1p, ib1, lane, w, b0i1);
    bf16x8 b0i2[1];
    preloadB<1>(iW2p, 128, w * 16, lane, b0i2);
    __syncthreads();

    f32x4 accV[2];
    gemm2(h_s, iW2p, accV, lane, w, b0i2[0]);

    // ---- bias + relu + cosine partials (each wave owns 16 cols) ----
    const int l15 = lane & 15, l4 = lane >> 4;
    const int col = w * 16 + l15;
    const float bu = ub2[col];
    const float bv = ib2[col];
    float pd[8], pu[8], pv[8];
    #pragma unroll
    for (int m = 0; m < 2; ++m)
        #pragma unroll
        for (int r = 0; r < 4; ++r) {
            float uval = accU[m][r] + bu;
            float vval = accV[m][r] + bv;
            uval = uval > 0.f ? uval : 0.f;
            vval = vval > 0.f ? vval : 0.f;
            int i = m * 4 + r;
            pd[i] = uval * vval;
            pu[i] = uval * uval;
            pv[i] = vval * vval;
        }
    #pragma unroll
    for (int off = 1; off < 16; off <<= 1) {
        #pragma unroll
        for (int i = 0; i < 8; ++i) {
            pd[i] += __shfl_xor(pd[i], off);
            pu[i] += __shfl_xor(pu[i], off);
            pv[i] += __shfl_xor(pv[i], off);
        }
    }
    if (l15 == 0) {
        #pragma unroll
        for (int m = 0; m < 2; ++m)
            #pragma unroll
            for (int r = 0; r < 4; ++r) {
                int row = m * 16 + l4 * 4 + r;
                int i = m * 4 + r;
                red[w][row][0] = pd[i];
                red[w][row][1] = pu[i];
                red[w][row][2] = pv[i];
            }
    }
    __syncthreads();

    // ---- final reduce + y + scatter ----
    if (tid < 32) {
        int row = tid;
        float d = 0.f, su = 0.f, sv = 0.f;
        #pragma unroll
        for (int ww = 0; ww < 8; ++ww) {
            d  += red[ww][row][0];
            su += red[ww][row][1];
            sv += red[ww][row][2];
        }
        float un = fmaxf(sqrtf(su), CEPS);
        float vn = fmaxf(sqrtf(sv), CEPS);
        int grow = row0 + row;
        float yv = d / (un * vn) - logf(sw[grow]);
        for (int j = 0; j < nn1; ++j) {
            int idx = grow - j;
            if (idx < 0) idx += B;
            out[idx * nn1 + j] = yv;
        }
    }
}

extern "C" void kernel_launch(void* const* d_in, const int* in_sizes, int n_in,
                              void* d_out, int out_size, void* d_ws, size_t ws_size,
                              hipStream_t stream)
{
    const int*   user_ids   = (const int*)  d_in[0];
    const int*   item_ids   = (const int*)  d_in[1];
    const float* sw         = (const float*)d_in[2];
    const float* user_table = (const float*)d_in[3];
    const float* item_table = (const float*)d_in[4];
    const float* uW1        = (const float*)d_in[5];
    const float* ub1        = (const float*)d_in[6];
    const float* uW2        = (const float*)d_in[7];
    const float* ub2        = (const float*)d_in[8];
    const float* iW1        = (const float*)d_in[9];
    const float* ib1        = (const float*)d_in[10];
    const float* iW2        = (const float*)d_in[11];
    const float* ib2        = (const float*)d_in[12];

    const int B   = in_sizes[2];       // 16384
    const int nn1 = out_size / B;      // n_neg + 1

    unsigned short* wp   = (unsigned short*)d_ws;
    unsigned short* uW1p = wp;               // 131072
    unsigned short* uW2p = wp + 131072;      // 32768
    unsigned short* iW1p = wp + 163840;      // 65536
    unsigned short* iW2p = wp + 229376;      // 32768
    float* out = (float*)d_out;

    pack_all<<<128, 256, 0, stream>>>(uW1, uW2, iW1, iW2,
                                      uW1p, uW2p, iW1p, iW2p);
    fused_sbc<<<B / 32, 512, 0, stream>>>(user_ids, item_ids,
                                          user_table, item_table,
                                          uW1p, ub1, uW2p, ub2,
                                          iW1p, ib1, iW2p, ib2,
                                          sw, out, B, nn1);
}

// Round 5
// 33.575 us; speedup vs baseline: 7.1270x; 1.0113x over previous
//
#include <hip/hip_runtime.h>
#include <math.h>

#define CEPS 1e-8f

typedef __attribute__((ext_vector_type(8))) short bf16x8;
typedef __attribute__((ext_vector_type(4))) float f32x4;
typedef __attribute__((ext_vector_type(4))) unsigned int u32x4;

__device__ __forceinline__ unsigned short f2bf(float f) {
    unsigned u = __builtin_bit_cast(unsigned, f);
    u += 0x7fffu + ((u >> 16) & 1u);            // round-nearest-even
    return (unsigned short)(u >> 16);
}

// Pack weights fp32 -> bf16, MFMA-B layout [K/8][N][8].
__global__ __launch_bounds__(256)
void pack_all(const float* __restrict__ uW1, const float* __restrict__ uW2,
              const float* __restrict__ iW1, const float* __restrict__ iW2,
              unsigned short* __restrict__ o1, unsigned short* __restrict__ o2,
              unsigned short* __restrict__ o3, unsigned short* __restrict__ o4)
{
    int g = blockIdx.x * 256 + threadIdx.x;     // 32768 entries
    const float* src; unsigned short* dst; int N; int base;
    if (g < 16384)      { src = uW1; dst = o1; N = 256; base = 0;     }
    else if (g < 20480) { src = uW2; dst = o2; N = 128; base = 16384; }
    else if (g < 28672) { src = iW1; dst = o3; N = 256; base = 20480; }
    else                { src = iW2; dst = o4; N = 128; base = 28672; }
    int i = g - base;
    int kg = i / N, n = i - kg * N;
    unsigned short tmp[8];
    #pragma unroll
    for (int j = 0; j < 8; ++j)
        tmp[j] = f2bf(src[(kg * 8 + j) * N + n]);
    *reinterpret_cast<bf16x8*>(dst + ((size_t)i << 3)) =
        *reinterpret_cast<bf16x8*>(tmp);
}

// --------- fused towers + cosine + score scatter -----------------------
// 64 rows/block, 1024 threads (16 waves). GEMM1: wave w owns cols w*16..+15,
// all 64 rows (m=4). GEMM2: wave w owns cols (w&7)*16..+15, rows (w>>3)*32..+31.

template<int F>
__device__ __forceinline__ void stage_emb(const int* __restrict__ ids,
                                          const float* __restrict__ table,
                                          unsigned short* e_s, int row0, int tid)
{
    constexpr int FC = F * 8;                    // 16B chunks per row
    constexpr int IT = (64 * FC) / 1024;
    int idv[IT];
    #pragma unroll
    for (int it = 0; it < IT; ++it) {
        int c = tid + it * 1024;
        int r = c / FC, f = (c % FC) >> 3;
        idv[it] = ids[(row0 + r) * F + f];
    }
    #pragma unroll
    for (int it = 0; it < IT; ++it) {
        int c = tid + it * 1024;
        int r = c / FC, rem = c % FC, ci = rem & 7;
        const float* src = table + (size_t)idv[it] * 64 + ci * 8;
        float4 aa = *reinterpret_cast<const float4*>(src);
        float4 bb = *reinterpret_cast<const float4*>(src + 4);
        u32x4 pk;
        pk.x = f2bf(aa.x) | ((unsigned)f2bf(aa.y) << 16);
        pk.y = f2bf(aa.z) | ((unsigned)f2bf(aa.w) << 16);
        pk.z = f2bf(bb.x) | ((unsigned)f2bf(bb.y) << 16);
        pk.w = f2bf(bb.z) | ((unsigned)f2bf(bb.w) << 16);
        int byte = r * (F * 128) + rem * 16;
        byte ^= (r & 7) << 4;
        *reinterpret_cast<u32x4*>(reinterpret_cast<char*>(e_s) + byte) = pk;
    }
}

template<int KB>
__device__ __forceinline__ bf16x8 loadA(const unsigned short* s, int rowbase,
                                        int ks, int m, int l15, int l4)
{
    int row = rowbase + m * 16 + l15;
    int byte = row * (KB * 2) + ks * 64 + l4 * 16;
    byte ^= (row & 7) << 4;
    return *reinterpret_cast<const bf16x8*>(
               reinterpret_cast<const char*>(s) + byte);
}

// GEMM1: h[64][256] = relu(e[64][K1] @ W1 + b1).  Wave: 16 cols, m=4.
template<int K1>
__device__ __forceinline__ void gemm1(
    const unsigned short* e_s, unsigned short* h_s,
    const unsigned short* __restrict__ W1p, const float* __restrict__ b1,
    int l15, int l4, int w, bf16x8 b0)
{
    constexpr int NKS = K1 / 32;
    const int col = w * 16 + l15;
    f32x4 acc[4];
    #pragma unroll
    for (int m = 0; m < 4; ++m) acc[m] = (f32x4){0.f, 0.f, 0.f, 0.f};

    const unsigned short* Wbase = W1p + (((l4 * 256) + col) << 3);
    bf16x8 aB[2][4], bB[2];
    bB[0] = b0;
    #pragma unroll
    for (int m = 0; m < 4; ++m) aB[0][m] = loadA<K1>(e_s, 0, 0, m, l15, l4);

    #pragma unroll
    for (int ks = 0; ks < NKS; ++ks) {
        const int cur = ks & 1, nxt = cur ^ 1;
        if (ks + 1 < NKS) {
            #pragma unroll
            for (int m = 0; m < 4; ++m)
                aB[nxt][m] = loadA<K1>(e_s, 0, ks + 1, m, l15, l4);
            bB[nxt] = *reinterpret_cast<const bf16x8*>(Wbase + (ks + 1) * 8192);
        }
        #pragma unroll
        for (int m = 0; m < 4; ++m)
            acc[m] = __builtin_amdgcn_mfma_f32_16x16x32_bf16(
                         aB[cur][m], bB[cur], acc[m], 0, 0, 0);
    }
    const float bias = b1[col];
    #pragma unroll
    for (int m = 0; m < 4; ++m)
        #pragma unroll
        for (int r = 0; r < 4; ++r) {
            int row = m * 16 + l4 * 4 + r;
            float v = acc[m][r] + bias;
            v = v > 0.f ? v : 0.f;
            int byte = (row * 256 + col) * 2;
            byte ^= (row & 7) << 4;
            *reinterpret_cast<unsigned short*>(
                reinterpret_cast<char*>(h_s) + byte) = f2bf(v);
        }
}

// GEMM2: acc[2] = h[rows 32*(w>>3)..+31][256] @ W2 (cols (w&7)*16..+15).
__device__ __forceinline__ void gemm2(
    const unsigned short* h_s, const unsigned short* __restrict__ W2p,
    f32x4 (&acc)[2], int l15, int l4, int w, bf16x8 b0)
{
    const int col = (w & 7) * 16 + l15;
    const int rowbase = (w >> 3) * 32;
    #pragma unroll
    for (int m = 0; m < 2; ++m) acc[m] = (f32x4){0.f, 0.f, 0.f, 0.f};

    const unsigned short* Wbase = W2p + (((l4 * 128) + col) << 3);
    bf16x8 aB[2][2], bB[2];
    bB[0] = b0;
    #pragma unroll
    for (int m = 0; m < 2; ++m) aB[0][m] = loadA<256>(h_s, rowbase, 0, m, l15, l4);

    #pragma unroll
    for (int ks = 0; ks < 8; ++ks) {
        const int cur = ks & 1, nxt = cur ^ 1;
        if (ks + 1 < 8) {
            #pragma unroll
            for (int m = 0; m < 2; ++m)
                aB[nxt][m] = loadA<256>(h_s, rowbase, ks + 1, m, l15, l4);
            bB[nxt] = *reinterpret_cast<const bf16x8*>(Wbase + (ks + 1) * 4096);
        }
        #pragma unroll
        for (int m = 0; m < 2; ++m)
            acc[m] = __builtin_amdgcn_mfma_f32_16x16x32_bf16(
                         aB[cur][m], bB[cur], acc[m], 0, 0, 0);
    }
}

__global__ __launch_bounds__(1024, 4)
void fused_sbc(const int* __restrict__ user_ids,  const int* __restrict__ item_ids,
               const float* __restrict__ user_table, const float* __restrict__ item_table,
               const unsigned short* __restrict__ uW1p, const float* __restrict__ ub1,
               const unsigned short* __restrict__ uW2p, const float* __restrict__ ub2,
               const unsigned short* __restrict__ iW1p, const float* __restrict__ ib1,
               const unsigned short* __restrict__ iW2p, const float* __restrict__ ib2,
               const float* __restrict__ sw, float* __restrict__ out,
               int B, int nn1)
{
    __shared__ unsigned short e_u[64 * 512];    // 64 KB
    __shared__ unsigned short e_i[64 * 256];    // 32 KB
    __shared__ unsigned short h_s[64 * 256];    // 32 KB
    __shared__ float red[8][64][3];             // 6 KB

    const int tid  = threadIdx.x;
    const int lane = tid & 63;
    const int w    = tid >> 6;
    const int l15  = lane & 15, l4 = lane >> 4;
    const int row0 = blockIdx.x * 64;

    // preload first user-W1 fragment; stage BOTH towers' embeddings up front
    bf16x8 b0u1 = *reinterpret_cast<const bf16x8*>(
                      uW1p + ((l4 * 256 + w * 16 + l15) << 3));
    stage_emb<8>(user_ids, user_table, e_u, row0, tid);
    stage_emb<4>(item_ids, item_table, e_i, row0, tid);
    __syncthreads();

    gemm1<512>(e_u, h_s, uW1p, ub1, l15, l4, w, b0u1);
    bf16x8 b0u2 = *reinterpret_cast<const bf16x8*>(
                      uW2p + ((l4 * 128 + (w & 7) * 16 + l15) << 3));
    bf16x8 b0i1 = *reinterpret_cast<const bf16x8*>(
                      iW1p + ((l4 * 256 + w * 16 + l15) << 3));
    __syncthreads();                       // h ready

    f32x4 accU[2];
    gemm2(h_s, uW2p, accU, l15, l4, w, b0u2);
    __syncthreads();                       // h reads done

    gemm1<256>(e_i, h_s, iW1p, ib1, l15, l4, w, b0i1);
    bf16x8 b0i2 = *reinterpret_cast<const bf16x8*>(
                      iW2p + ((l4 * 128 + (w & 7) * 16 + l15) << 3));
    __syncthreads();                       // item h ready

    f32x4 accV[2];
    gemm2(h_s, iW2p, accV, l15, l4, w, b0i2);

    // ---- bias + relu + cosine partials (wave owns 16 cols × 32 rows) ----
    const int col = (w & 7) * 16 + l15;
    const float bu = ub2[col];
    const float bv = ib2[col];
    float pd[8], pu[8], pv[8];
    #pragma unroll
    for (int m = 0; m < 2; ++m)
        #pragma unroll
        for (int r = 0; r < 4; ++r) {
            float uval = accU[m][r] + bu;
            float vval = accV[m][r] + bv;
            uval = uval > 0.f ? uval : 0.f;
            vval = vval > 0.f ? vval : 0.f;
            int i = m * 4 + r;
            pd[i] = uval * vval;
            pu[i] = uval * uval;
            pv[i] = vval * vval;
        }
    #pragma unroll
    for (int off = 1; off < 16; off <<= 1) {
        #pragma unroll
        for (int i = 0; i < 8; ++i) {
            pd[i] += __shfl_xor(pd[i], off);
            pu[i] += __shfl_xor(pu[i], off);
            pv[i] += __shfl_xor(pv[i], off);
        }
    }
    if (l15 == 0) {
        const int rowbase = (w >> 3) * 32;
        #pragma unroll
        for (int m = 0; m < 2; ++m)
            #pragma unroll
            for (int r = 0; r < 4; ++r) {
                int row = rowbase + m * 16 + l4 * 4 + r;
                int i = m * 4 + r;
                red[w & 7][row][0] = pd[i];
                red[w & 7][row][1] = pu[i];
                red[w & 7][row][2] = pv[i];
            }
    }
    __syncthreads();

    // ---- final reduce + y + scatter ----
    if (tid < 64) {
        int row = tid;
        float d = 0.f, su = 0.f, sv = 0.f;
        #pragma unroll
        for (int cg = 0; cg < 8; ++cg) {
            d  += red[cg][row][0];
            su += red[cg][row][1];
            sv += red[cg][row][2];
        }
        float un = fmaxf(sqrtf(su), CEPS);
        float vn = fmaxf(sqrtf(sv), CEPS);
        int grow = row0 + row;
        float yv = d / (un * vn) - logf(sw[grow]);
        for (int j = 0; j < nn1; ++j) {
            int idx = grow - j;
            if (idx < 0) idx += B;
            out[idx * nn1 + j] = yv;
        }
    }
}

extern "C" void kernel_launch(void* const* d_in, const int* in_sizes, int n_in,
                              void* d_out, int out_size, void* d_ws, size_t ws_size,
                              hipStream_t stream)
{
    const int*   user_ids   = (const int*)  d_in[0];
    const int*   item_ids   = (const int*)  d_in[1];
    const float* sw         = (const float*)d_in[2];
    const float* user_table = (const float*)d_in[3];
    const float* item_table = (const float*)d_in[4];
    const float* uW1        = (const float*)d_in[5];
    const float* ub1        = (const float*)d_in[6];
    const float* uW2        = (const float*)d_in[7];
    const float* ub2        = (const float*)d_in[8];
    const float* iW1        = (const float*)d_in[9];
    const float* ib1        = (const float*)d_in[10];
    const float* iW2        = (const float*)d_in[11];
    const float* ib2        = (const float*)d_in[12];

    const int B   = in_sizes[2];       // 16384
    const int nn1 = out_size / B;      // n_neg + 1

    unsigned short* wp   = (unsigned short*)d_ws;
    unsigned short* uW1p = wp;               // 131072
    unsigned short* uW2p = wp + 131072;      // 32768
    unsigned short* iW1p = wp + 163840;      // 65536
    unsigned short* iW2p = wp + 229376;      // 32768
    float* out = (float*)d_out;

    pack_all<<<128, 256, 0, stream>>>(uW1, uW2, iW1, iW2,
                                      uW1p, uW2p, iW1p, iW2p);
    fused_sbc<<<B / 64, 1024, 0, stream>>>(user_ids, item_ids,
                                           user_table, item_table,
                                           uW1p, ub1, uW2p, ub2,
                                           iW1p, ib1, iW2p, ib2,
                                           sw, out, B, nn1);
}

// Round 6
// 32.399 us; speedup vs baseline: 7.3857x; 1.0363x over previous
//
#include <hip/hip_runtime.h>
#include <math.h>

#define CEPS 1e-8f

typedef __attribute__((ext_vector_type(8))) short bf16x8;
typedef __attribute__((ext_vector_type(4))) float f32x4;
typedef __attribute__((ext_vector_type(4))) unsigned int u32x4;

__device__ __forceinline__ unsigned short f2bf(float f) {
    unsigned u = __builtin_bit_cast(unsigned, f);
    u += 0x7fffu + ((u >> 16) & 1u);            // round-nearest-even
    return (unsigned short)(u >> 16);
}

// Pack weights fp32 -> bf16, MFMA-B layout [K/8][N][8].
__global__ __launch_bounds__(256)
void pack_all(const float* __restrict__ uW1, const float* __restrict__ uW2,
              const float* __restrict__ iW1, const float* __restrict__ iW2,
              unsigned short* __restrict__ o1, unsigned short* __restrict__ o2,
              unsigned short* __restrict__ o3, unsigned short* __restrict__ o4)
{
    int g = blockIdx.x * 256 + threadIdx.x;     // 32768 entries
    const float* src; unsigned short* dst; int N; int base;
    if (g < 16384)      { src = uW1; dst = o1; N = 256; base = 0;     }
    else if (g < 20480) { src = uW2; dst = o2; N = 128; base = 16384; }
    else if (g < 28672) { src = iW1; dst = o3; N = 256; base = 20480; }
    else                { src = iW2; dst = o4; N = 128; base = 28672; }
    int i = g - base;
    int kg = i / N, n = i - kg * N;
    unsigned short tmp[8];
    #pragma unroll
    for (int j = 0; j < 8; ++j)
        tmp[j] = f2bf(src[(kg * 8 + j) * N + n]);
    *reinterpret_cast<bf16x8*>(dst + ((size_t)i << 3)) =
        *reinterpret_cast<bf16x8*>(tmp);
}

// --------- fused towers (wave-parallel) + cosine + score scatter ---------
// 64 rows/block, 1024 threads (16 waves).
// Waves 0-7: user tower.  Waves 8-15: item tower.  Runs concurrently.

template<int F>
__device__ __forceinline__ void stage_emb(const int* __restrict__ ids,
                                          const float* __restrict__ table,
                                          unsigned short* e_s, int row0, int tid)
{
    constexpr int FC = F * 8;                    // 16B chunks per row
    constexpr int IT = (64 * FC) / 1024;
    int idv[IT];
    #pragma unroll
    for (int it = 0; it < IT; ++it) {
        int c = tid + it * 1024;
        int r = c / FC, f = (c % FC) >> 3;
        idv[it] = ids[(row0 + r) * F + f];
    }
    #pragma unroll
    for (int it = 0; it < IT; ++it) {
        int c = tid + it * 1024;
        int r = c / FC, rem = c % FC, ci = rem & 7;
        const float* src = table + (size_t)idv[it] * 64 + ci * 8;
        float4 aa = *reinterpret_cast<const float4*>(src);
        float4 bb = *reinterpret_cast<const float4*>(src + 4);
        u32x4 pk;
        pk.x = f2bf(aa.x) | ((unsigned)f2bf(aa.y) << 16);
        pk.y = f2bf(aa.z) | ((unsigned)f2bf(aa.w) << 16);
        pk.z = f2bf(bb.x) | ((unsigned)f2bf(bb.y) << 16);
        pk.w = f2bf(bb.z) | ((unsigned)f2bf(bb.w) << 16);
        int byte = r * (F * 128) + rem * 16;
        byte ^= (r & 7) << 4;
        *reinterpret_cast<u32x4*>(reinterpret_cast<char*>(e_s) + byte) = pk;
    }
}

template<int KB>
__device__ __forceinline__ bf16x8 loadA(const unsigned short* s, int ks, int m,
                                        int l15, int l4)
{
    int row = m * 16 + l15;
    int byte = row * (KB * 2) + ks * 64 + l4 * 16;
    byte ^= (row & 7) << 4;
    return *reinterpret_cast<const bf16x8*>(
               reinterpret_cast<const char*>(s) + byte);
}

// GEMM1: h[64][256] = relu(e[64][K1] @ W1 + b1).  Wave: 32 cols (n=2), m=4.
template<int K1>
__device__ __forceinline__ void gemm1(
    const unsigned short* e_s, unsigned short* h_s,
    const unsigned short* __restrict__ W1p, const float* __restrict__ b1,
    int l15, int l4, int wl, const bf16x8* b0)
{
    constexpr int NKS = K1 / 32;
    const int colbase = wl * 32;
    f32x4 acc[4][2];
    #pragma unroll
    for (int m = 0; m < 4; ++m)
        #pragma unroll
        for (int n = 0; n < 2; ++n) acc[m][n] = (f32x4){0.f, 0.f, 0.f, 0.f};

    const unsigned short* Wbase = W1p + (((l4 * 256) + colbase + l15) << 3);
    bf16x8 aB[2][4], bB[2][2];
    bB[0][0] = b0[0];
    bB[0][1] = b0[1];
    #pragma unroll
    for (int m = 0; m < 4; ++m) aB[0][m] = loadA<K1>(e_s, 0, m, l15, l4);

    #pragma unroll
    for (int ks = 0; ks < NKS; ++ks) {
        const int cur = ks & 1, nxt = cur ^ 1;
        if (ks + 1 < NKS) {
            #pragma unroll
            for (int m = 0; m < 4; ++m)
                aB[nxt][m] = loadA<K1>(e_s, ks + 1, m, l15, l4);
            #pragma unroll
            for (int n = 0; n < 2; ++n)
                bB[nxt][n] = *reinterpret_cast<const bf16x8*>(
                                 Wbase + (ks + 1) * 8192 + (n << 7));
        }
        #pragma unroll
        for (int n = 0; n < 2; ++n)
            #pragma unroll
            for (int m = 0; m < 4; ++m)
                acc[m][n] = __builtin_amdgcn_mfma_f32_16x16x32_bf16(
                                aB[cur][m], bB[cur][n], acc[m][n], 0, 0, 0);
    }
    #pragma unroll
    for (int n = 0; n < 2; ++n) {
        int col = colbase + n * 16 + l15;
        float bias = b1[col];
        #pragma unroll
        for (int m = 0; m < 4; ++m)
            #pragma unroll
            for (int r = 0; r < 4; ++r) {
                int row = m * 16 + l4 * 4 + r;
                float v = acc[m][n][r] + bias;
                v = v > 0.f ? v : 0.f;
                int byte = (row * 256 + col) * 2;
                byte ^= (row & 7) << 4;
                *reinterpret_cast<unsigned short*>(
                    reinterpret_cast<char*>(h_s) + byte) = f2bf(v);
            }
    }
}

// GEMM2: acc[4] = h[64][256] @ W2 (cols wl*16..+15), m=4, no epilogue.
__device__ __forceinline__ void gemm2(
    const unsigned short* h_s, const unsigned short* __restrict__ W2p,
    f32x4 (&acc)[4], int l15, int l4, int wl, bf16x8 b0)
{
    const int col = wl * 16 + l15;
    #pragma unroll
    for (int m = 0; m < 4; ++m) acc[m] = (f32x4){0.f, 0.f, 0.f, 0.f};

    const unsigned short* Wbase = W2p + (((l4 * 128) + col) << 3);
    bf16x8 aB[2][4], bB[2];
    bB[0] = b0;
    #pragma unroll
    for (int m = 0; m < 4; ++m) aB[0][m] = loadA<256>(h_s, 0, m, l15, l4);

    #pragma unroll
    for (int ks = 0; ks < 8; ++ks) {
        const int cur = ks & 1, nxt = cur ^ 1;
        if (ks + 1 < 8) {
            #pragma unroll
            for (int m = 0; m < 4; ++m)
                aB[nxt][m] = loadA<256>(h_s, ks + 1, m, l15, l4);
            bB[nxt] = *reinterpret_cast<const bf16x8*>(Wbase + (ks + 1) * 4096);
        }
        #pragma unroll
        for (int m = 0; m < 4; ++m)
            acc[m] = __builtin_amdgcn_mfma_f32_16x16x32_bf16(
                         aB[cur][m], bB[cur], acc[m], 0, 0, 0);
    }
}

__global__ __launch_bounds__(1024)
void fused_sbc(const int* __restrict__ user_ids,  const int* __restrict__ item_ids,
               const float* __restrict__ user_table, const float* __restrict__ item_table,
               const unsigned short* __restrict__ uW1p, const float* __restrict__ ub1,
               const unsigned short* __restrict__ uW2p, const float* __restrict__ ub2,
               const unsigned short* __restrict__ iW1p, const float* __restrict__ ib1,
               const unsigned short* __restrict__ iW2p, const float* __restrict__ ib2,
               const float* __restrict__ sw, float* __restrict__ out,
               int B, int nn1)
{
    // 160 KB LDS, carved; V_lds / red overlay regions retired after GEMM1.
    __shared__ __align__(16) unsigned short smem[81920];
    unsigned short* e_u = smem;                  // [64][512]  64 KB
    unsigned short* e_i = smem + 32768;          // [64][256]  32 KB
    unsigned short* h_u = smem + 49152;          // [64][256]  32 KB
    unsigned short* h_i = smem + 65536;          // [64][256]  32 KB
    float* V_lds = reinterpret_cast<float*>(smem);          // [64][132] over e_u
    float* red   = reinterpret_cast<float*>(smem + 32768);  // [8][64][3] over e_i

    const int tid  = threadIdx.x;
    const int lane = tid & 63;
    const int w    = tid >> 6;
    const int l15  = lane & 15, l4 = lane >> 4;
    const int role = w >> 3;                     // 0 = user, 1 = item
    const int wl   = w & 7;
    const int row0 = blockIdx.x * 64;

    const unsigned short* W1sel = role ? iW1p : uW1p;
    const unsigned short* W2sel = role ? iW2p : uW2p;

    // preload first GEMM1 B-fragments (in flight across staging + barrier)
    bf16x8 b0g1[2];
    {
        const unsigned short* base = W1sel + ((l4 * 256 + wl * 32 + l15) << 3);
        b0g1[0] = *reinterpret_cast<const bf16x8*>(base);
        b0g1[1] = *reinterpret_cast<const bf16x8*>(base + 128);
    }
    stage_emb<8>(user_ids, user_table, e_u, row0, tid);
    stage_emb<4>(item_ids, item_table, e_i, row0, tid);
    __syncthreads();                             // B1: embeddings staged

    if (role == 0) gemm1<512>(e_u, h_u, uW1p, ub1, l15, l4, wl, b0g1);
    else           gemm1<256>(e_i, h_i, iW1p, ib1, l15, l4, wl, b0g1);
    bf16x8 b0g2 = *reinterpret_cast<const bf16x8*>(
                      W2sel + ((l4 * 128 + wl * 16 + l15) << 3));
    __syncthreads();                             // B2: h_u, h_i ready

    f32x4 acc2[4];
    if (role == 0) gemm2(h_u, uW2p, acc2, l15, l4, wl, b0g2);
    else           gemm2(h_i, iW2p, acc2, l15, l4, wl, b0g2);

    const int col = wl * 16 + l15;

    // item waves: relu(V), publish V + ||v||^2 partials
    if (role == 1) {
        const float bv = ib2[col];
        float pv[16];
        #pragma unroll
        for (int m = 0; m < 4; ++m)
            #pragma unroll
            for (int r = 0; r < 4; ++r) {
                float vv = acc2[m][r] + bv;
                vv = vv > 0.f ? vv : 0.f;
                int row = m * 16 + l4 * 4 + r;
                V_lds[row * 132 + col] = vv;
                pv[m * 4 + r] = vv * vv;
            }
        #pragma unroll
        for (int off = 1; off < 16; off <<= 1)
            #pragma unroll
            for (int i = 0; i < 16; ++i)
                pv[i] += __shfl_xor(pv[i], off);
        if (l15 == 0) {
            #pragma unroll
            for (int m = 0; m < 4; ++m)
                #pragma unroll
                for (int r = 0; r < 4; ++r) {
                    int row = m * 16 + l4 * 4 + r;
                    red[(wl * 64 + row) * 3 + 2] = pv[m * 4 + r];
                }
        }
    }
    __syncthreads();                             // B3: V published

    // user waves: relu(U), dot + ||u||^2 partials
    if (role == 0) {
        const float bu = ub2[col];
        float pd[16], pu[16];
        #pragma unroll
        for (int m = 0; m < 4; ++m)
            #pragma unroll
            for (int r = 0; r < 4; ++r) {
                float uu = acc2[m][r] + bu;
                uu = uu > 0.f ? uu : 0.f;
                int row = m * 16 + l4 * 4 + r;
                float vv = V_lds[row * 132 + col];
                pd[m * 4 + r] = uu * vv;
                pu[m * 4 + r] = uu * uu;
            }
        #pragma unroll
        for (int off = 1; off < 16; off <<= 1)
            #pragma unroll
            for (int i = 0; i < 16; ++i) {
                pd[i] += __shfl_xor(pd[i], off);
                pu[i] += __shfl_xor(pu[i], off);
            }
        if (l15 == 0) {
            #pragma unroll
            for (int m = 0; m < 4; ++m)
                #pragma unroll
                for (int r = 0; r < 4; ++r) {
                    int row = m * 16 + l4 * 4 + r;
                    red[(wl * 64 + row) * 3 + 0] = pd[m * 4 + r];
                    red[(wl * 64 + row) * 3 + 1] = pu[m * 4 + r];
                }
        }
    }
    __syncthreads();                             // B4: partials in red

    // final reduce + y + scatter
    if (tid < 64) {
        int row = tid;
        float d = 0.f, su = 0.f, sv = 0.f;
        #pragma unroll
        for (int cg = 0; cg < 8; ++cg) {
            d  += red[(cg * 64 + row) * 3 + 0];
            su += red[(cg * 64 + row) * 3 + 1];
            sv += red[(cg * 64 + row) * 3 + 2];
        }
        float un = fmaxf(sqrtf(su), CEPS);
        float vn = fmaxf(sqrtf(sv), CEPS);
        int grow = row0 + row;
        float yv = d / (un * vn) - logf(sw[grow]);
        for (int j = 0; j < nn1; ++j) {
            int idx = grow - j;
            if (idx < 0) idx += B;
            out[idx * nn1 + j] = yv;
        }
    }
}

extern "C" void kernel_launch(void* const* d_in, const int* in_sizes, int n_in,
                              void* d_out, int out_size, void* d_ws, size_t ws_size,
                              hipStream_t stream)
{
    const int*   user_ids   = (const int*)  d_in[0];
    const int*   item_ids   = (const int*)  d_in[1];
    const float* sw         = (const float*)d_in[2];
    const float* user_table = (const float*)d_in[3];
    const float* item_table = (const float*)d_in[4];
    const float* uW1        = (const float*)d_in[5];
    const float* ub1        = (const float*)d_in[6];
    const float* uW2        = (const float*)d_in[7];
    const float* ub2        = (const float*)d_in[8];
    const float* iW1        = (const float*)d_in[9];
    const float* ib1        = (const float*)d_in[10];
    const float* iW2        = (const float*)d_in[11];
    const float* ib2        = (const float*)d_in[12];

    const int B   = in_sizes[2];       // 16384
    const int nn1 = out_size / B;      // n_neg + 1

    unsigned short* wp   = (unsigned short*)d_ws;
    unsigned short* uW1p = wp;               // 131072
    unsigned short* uW2p = wp + 131072;      // 32768
    unsigned short* iW1p = wp + 163840;      // 65536
    unsigned short* iW2p = wp + 229376;      // 32768
    float* out = (float*)d_out;

    pack_all<<<128, 256, 0, stream>>>(uW1, uW2, iW1, iW2,
                                      uW1p, uW2p, iW1p, iW2p);
    fused_sbc<<<B / 64, 1024, 0, stream>>>(user_ids, item_ids,
                                           user_table, item_table,
                                           uW1p, ub1, uW2p, ub2,
                                           iW1p, ib1, iW2p, ib2,
                                           sw, out, B, nn1);
}

// Round 7
// 28.563 us; speedup vs baseline: 8.3776x; 1.1343x over previous
//
#include <hip/hip_runtime.h>
#include <math.h>

#define CEPS 1e-8f

typedef __attribute__((ext_vector_type(8))) short bf16x8;
typedef __attribute__((ext_vector_type(4))) float f32x4;
typedef __attribute__((ext_vector_type(4))) unsigned int u32x4;
typedef __attribute__((ext_vector_type(2))) unsigned int u32x2;

__device__ __forceinline__ unsigned short f2bf(float f) {
    unsigned u = __builtin_bit_cast(unsigned, f);
    u += 0x7fffu + ((u >> 16) & 1u);            // round-nearest-even
    return (unsigned short)(u >> 16);
}

// Pack weights fp32 -> bf16, MFMA fragment layout [K/8][N][8].
__global__ __launch_bounds__(256)
void pack_all(const float* __restrict__ uW1, const float* __restrict__ uW2,
              const float* __restrict__ iW1, const float* __restrict__ iW2,
              unsigned short* __restrict__ o1, unsigned short* __restrict__ o2,
              unsigned short* __restrict__ o3, unsigned short* __restrict__ o4)
{
    int g = blockIdx.x * 256 + threadIdx.x;     // 32768 entries
    const float* src; unsigned short* dst; int N; int base;
    if (g < 16384)      { src = uW1; dst = o1; N = 256; base = 0;     }
    else if (g < 20480) { src = uW2; dst = o2; N = 128; base = 16384; }
    else if (g < 28672) { src = iW1; dst = o3; N = 256; base = 20480; }
    else                { src = iW2; dst = o4; N = 128; base = 28672; }
    int i = g - base;
    int kg = i / N, n = i - kg * N;
    unsigned short tmp[8];
    #pragma unroll
    for (int j = 0; j < 8; ++j)
        tmp[j] = f2bf(src[(kg * 8 + j) * N + n]);
    *reinterpret_cast<bf16x8*>(dst + ((size_t)i << 3)) =
        *reinterpret_cast<bf16x8*>(tmp);
}

// --------- fused towers (wave-parallel, swapped-operand MFMA) ------------
// 64 rows/block, 1024 threads (16 waves). Waves 0-7 user, 8-15 item.
// GEMM output is computed transposed: D[wcol][erow] via mfma(Wfrag, efrag).

template<int F>
__device__ __forceinline__ void stage_emb(const int* __restrict__ ids,
                                          const float* __restrict__ table,
                                          unsigned short* e_s, int row0, int tid)
{
    constexpr int FC = F * 8;                    // 16B chunks per row
    constexpr int IT = (64 * FC) / 1024;
    int idv[IT];
    #pragma unroll
    for (int it = 0; it < IT; ++it) {
        int c = tid + it * 1024;
        int r = c / FC, f = (c % FC) >> 3;
        idv[it] = ids[(row0 + r) * F + f];
    }
    #pragma unroll
    for (int it = 0; it < IT; ++it) {
        int c = tid + it * 1024;
        int r = c / FC, rem = c % FC;
        const float* src = table + (size_t)idv[it] * 64 + (rem & 7) * 8;
        float4 aa = *reinterpret_cast<const float4*>(src);
        float4 bb = *reinterpret_cast<const float4*>(src + 4);
        u32x4 pk;
        pk.x = f2bf(aa.x) | ((unsigned)f2bf(aa.y) << 16);
        pk.y = f2bf(aa.z) | ((unsigned)f2bf(aa.w) << 16);
        pk.z = f2bf(bb.x) | ((unsigned)f2bf(bb.y) << 16);
        pk.w = f2bf(bb.z) | ((unsigned)f2bf(bb.w) << 16);
        int byte = r * (F * 128) + rem * 16;
        byte ^= (r & 7) << 4;
        *reinterpret_cast<u32x4*>(reinterpret_cast<char*>(e_s) + byte) = pk;
    }
}

// LDS fragment read: 8 K-contiguous bf16 of row (ni*16+l15) at k-slice l4.
template<int KB>
__device__ __forceinline__ bf16x8 loadA(const unsigned short* s, int ks, int ni,
                                        int l15, int l4)
{
    int row = ni * 16 + l15;
    int byte = row * (KB * 2) + ks * 64 + l4 * 16;
    byte ^= (row & 7) << 4;
    return *reinterpret_cast<const bf16x8*>(
               reinterpret_cast<const char*>(s) + byte);
}

// GEMM1 (swapped): h^T tiles. Wave owns w-cols [wl*32, wl*32+32), all 64 rows.
template<int K1>
__device__ __forceinline__ void gemm1(
    const unsigned short* e_s, unsigned short* h_s,
    const unsigned short* __restrict__ W1p, const float* __restrict__ b1,
    int l15, int l4, int wl, const bf16x8* w0)
{
    constexpr int NKS = K1 / 32;
    f32x4 acc[2][4];
    #pragma unroll
    for (int mi = 0; mi < 2; ++mi)
        #pragma unroll
        for (int ni = 0; ni < 4; ++ni) acc[mi][ni] = (f32x4){0.f, 0.f, 0.f, 0.f};

    const unsigned short* Wbase = W1p + ((l4 * 256 + wl * 32 + l15) << 3);
    bf16x8 wf[3][2], ef[2][4];
    wf[0][0] = w0[0];
    wf[0][1] = w0[1];
    #pragma unroll
    for (int mi = 0; mi < 2; ++mi)
        wf[1][mi] = *reinterpret_cast<const bf16x8*>(Wbase + 8192 + (mi << 7));
    #pragma unroll
    for (int ni = 0; ni < 4; ++ni) ef[0][ni] = loadA<K1>(e_s, 0, ni, l15, l4);

    #pragma unroll
    for (int ks = 0; ks < NKS; ++ks) {
        if (ks + 2 < NKS) {
            #pragma unroll
            for (int mi = 0; mi < 2; ++mi)
                wf[(ks + 2) % 3][mi] = *reinterpret_cast<const bf16x8*>(
                    Wbase + (ks + 2) * 8192 + (mi << 7));
        }
        if (ks + 1 < NKS) {
            #pragma unroll
            for (int ni = 0; ni < 4; ++ni)
                ef[(ks + 1) & 1][ni] = loadA<K1>(e_s, ks + 1, ni, l15, l4);
        }
        __builtin_amdgcn_s_setprio(1);
        #pragma unroll
        for (int mi = 0; mi < 2; ++mi)
            #pragma unroll
            for (int ni = 0; ni < 4; ++ni)
                acc[mi][ni] = __builtin_amdgcn_mfma_f32_16x16x32_bf16(
                                  wf[ks % 3][mi], ef[ks & 1][ni], acc[mi][ni], 0, 0, 0);
        __builtin_amdgcn_s_setprio(0);
    }
    // epilogue: bias + relu; lane holds 4 consecutive w-cols of one row -> b64
    float4 bias[2];
    bias[0] = *reinterpret_cast<const float4*>(&b1[wl * 32 + l4 * 4]);
    bias[1] = *reinterpret_cast<const float4*>(&b1[wl * 32 + 16 + l4 * 4]);
    #pragma unroll
    for (int mi = 0; mi < 2; ++mi) {
        const float4 bb = bias[mi];
        #pragma unroll
        for (int ni = 0; ni < 4; ++ni) {
            float v0 = acc[mi][ni][0] + bb.x; v0 = v0 > 0.f ? v0 : 0.f;
            float v1 = acc[mi][ni][1] + bb.y; v1 = v1 > 0.f ? v1 : 0.f;
            float v2 = acc[mi][ni][2] + bb.z; v2 = v2 > 0.f ? v2 : 0.f;
            float v3 = acc[mi][ni][3] + bb.w; v3 = v3 > 0.f ? v3 : 0.f;
            u32x2 d;
            d.x = f2bf(v0) | ((unsigned)f2bf(v1) << 16);
            d.y = f2bf(v2) | ((unsigned)f2bf(v3) << 16);
            int row = ni * 16 + l15;
            int w0c = wl * 32 + mi * 16 + l4 * 4;
            int byte = (row * 256 + w0c) * 2;
            byte ^= (row & 7) << 4;
            *reinterpret_cast<u32x2*>(reinterpret_cast<char*>(h_s) + byte) = d;
        }
    }
}

// GEMM2 (swapped): wave owns out-cols [wl*16, wl*16+16), all 64 rows.
__device__ __forceinline__ void gemm2(
    const unsigned short* h_s, const unsigned short* __restrict__ W2p,
    f32x4 (&acc)[4], int l15, int l4, int wl, bf16x8 w0)
{
    #pragma unroll
    for (int ni = 0; ni < 4; ++ni) acc[ni] = (f32x4){0.f, 0.f, 0.f, 0.f};

    const unsigned short* Wbase = W2p + ((l4 * 128 + wl * 16 + l15) << 3);
    bf16x8 wf[3], hf[2][4];
    wf[0] = w0;
    wf[1] = *reinterpret_cast<const bf16x8*>(Wbase + 4096);
    #pragma unroll
    for (int ni = 0; ni < 4; ++ni) hf[0][ni] = loadA<256>(h_s, 0, ni, l15, l4);

    #pragma unroll
    for (int ks = 0; ks < 8; ++ks) {
        if (ks + 2 < 8)
            wf[(ks + 2) % 3] = *reinterpret_cast<const bf16x8*>(
                                   Wbase + (ks + 2) * 4096);
        if (ks + 1 < 8) {
            #pragma unroll
            for (int ni = 0; ni < 4; ++ni)
                hf[(ks + 1) & 1][ni] = loadA<256>(h_s, ks + 1, ni, l15, l4);
        }
        __builtin_amdgcn_s_setprio(1);
        #pragma unroll
        for (int ni = 0; ni < 4; ++ni)
            acc[ni] = __builtin_amdgcn_mfma_f32_16x16x32_bf16(
                          wf[ks % 3], hf[ks & 1][ni], acc[ni], 0, 0, 0);
        __builtin_amdgcn_s_setprio(0);
    }
}

__global__ __launch_bounds__(1024, 4)
void fused_sbc(const int* __restrict__ user_ids,  const int* __restrict__ item_ids,
               const float* __restrict__ user_table, const float* __restrict__ item_table,
               const unsigned short* __restrict__ uW1p, const float* __restrict__ ub1,
               const unsigned short* __restrict__ uW2p, const float* __restrict__ ub2,
               const unsigned short* __restrict__ iW1p, const float* __restrict__ ib1,
               const unsigned short* __restrict__ iW2p, const float* __restrict__ ib2,
               const float* __restrict__ sw, float* __restrict__ out,
               int B, int nn1)
{
    __shared__ __align__(16) unsigned short smem[81920];   // 160 KB
    unsigned short* e_u = smem;                  // [64][512]  64 KB
    unsigned short* e_i = smem + 32768;          // [64][256]  32 KB
    unsigned short* h_u = smem + 49152;          // [64][256]  32 KB
    unsigned short* h_i = smem + 65536;          // [64][256]  32 KB
    float* V_lds = reinterpret_cast<float*>(smem);          // [64][129] over e_u
    float* red   = reinterpret_cast<float*>(smem + 32768);  // [8][64][3] over e_i

    const int tid  = threadIdx.x;
    const int lane = tid & 63;
    const int w    = tid >> 6;
    const int l15  = lane & 15, l4 = lane >> 4;
    const int role = w >> 3;                     // 0 = user, 1 = item
    const int wl   = w & 7;
    const int row0 = blockIdx.x * 64;

    const unsigned short* W1sel = role ? iW1p : uW1p;
    const unsigned short* W2sel = role ? iW2p : uW2p;

    // preload ks=0 weight fragments (in flight across staging + barrier)
    bf16x8 w0g1[2];
    {
        const unsigned short* base = W1sel + ((l4 * 256 + wl * 32 + l15) << 3);
        w0g1[0] = *reinterpret_cast<const bf16x8*>(base);
        w0g1[1] = *reinterpret_cast<const bf16x8*>(base + 128);
    }
    stage_emb<8>(user_ids, user_table, e_u, row0, tid);
    stage_emb<4>(item_ids, item_table, e_i, row0, tid);
    __syncthreads();                             // B1: embeddings staged

    if (role == 0) gemm1<512>(e_u, h_u, uW1p, ub1, l15, l4, wl, w0g1);
    else           gemm1<256>(e_i, h_i, iW1p, ib1, l15, l4, wl, w0g1);
    bf16x8 w0g2 = *reinterpret_cast<const bf16x8*>(
                      W2sel + ((l4 * 128 + wl * 16 + l15) << 3));
    __syncthreads();                             // B2: h_u, h_i ready

    f32x4 acc2[4];
    if (role == 0) gemm2(h_u, uW2p, acc2, l15, l4, wl, w0g2);
    else           gemm2(h_i, iW2p, acc2, l15, l4, wl, w0g2);

    const int colb = wl * 16 + l4 * 4;           // thread's 4 output cols

    // item waves: relu(V) -> V_lds + ||v||^2 partials
    if (role == 1) {
        const float4 bv = *reinterpret_cast<const float4*>(&ib2[colb]);
        float pv[4];
        #pragma unroll
        for (int ni = 0; ni < 4; ++ni) {
            int row = ni * 16 + l15;
            float v0 = acc2[ni][0] + bv.x; v0 = v0 > 0.f ? v0 : 0.f;
            float v1 = acc2[ni][1] + bv.y; v1 = v1 > 0.f ? v1 : 0.f;
            float v2 = acc2[ni][2] + bv.z; v2 = v2 > 0.f ? v2 : 0.f;
            float v3 = acc2[ni][3] + bv.w; v3 = v3 > 0.f ? v3 : 0.f;
            V_lds[row * 129 + colb + 0] = v0;
            V_lds[row * 129 + colb + 1] = v1;
            V_lds[row * 129 + colb + 2] = v2;
            V_lds[row * 129 + colb + 3] = v3;
            pv[ni] = v0 * v0 + v1 * v1 + v2 * v2 + v3 * v3;
        }
        #pragma unroll
        for (int ni = 0; ni < 4; ++ni) {
            pv[ni] += __shfl_xor(pv[ni], 16);
            pv[ni] += __shfl_xor(pv[ni], 32);
        }
        if (l4 == 0) {
            #pragma unroll
            for (int ni = 0; ni < 4; ++ni)
                red[(wl * 64 + ni * 16 + l15) * 3 + 2] = pv[ni];
        }
    }
    __syncthreads();                             // B3: V published

    // user waves: relu(U), dot + ||u||^2 partials
    if (role == 0) {
        const float4 bu = *reinterpret_cast<const float4*>(&ub2[colb]);
        float pd[4], pu[4];
        #pragma unroll
        for (int ni = 0; ni < 4; ++ni) {
            int row = ni * 16 + l15;
            float u0 = acc2[ni][0] + bu.x; u0 = u0 > 0.f ? u0 : 0.f;
            float u1 = acc2[ni][1] + bu.y; u1 = u1 > 0.f ? u1 : 0.f;
            float u2 = acc2[ni][2] + bu.z; u2 = u2 > 0.f ? u2 : 0.f;
            float u3 = acc2[ni][3] + bu.w; u3 = u3 > 0.f ? u3 : 0.f;
            float v0 = V_lds[row * 129 + colb + 0];
            float v1 = V_lds[row * 129 + colb + 1];
            float v2 = V_lds[row * 129 + colb + 2];
            float v3 = V_lds[row * 129 + colb + 3];
            pd[ni] = u0 * v0 + u1 * v1 + u2 * v2 + u3 * v3;
            pu[ni] = u0 * u0 + u1 * u1 + u2 * u2 + u3 * u3;
        }
        #pragma unroll
        for (int ni = 0; ni < 4; ++ni) {
            pd[ni] += __shfl_xor(pd[ni], 16);
            pd[ni] += __shfl_xor(pd[ni], 32);
            pu[ni] += __shfl_xor(pu[ni], 16);
            pu[ni] += __shfl_xor(pu[ni], 32);
        }
        if (l4 == 0) {
            #pragma unroll
            for (int ni = 0; ni < 4; ++ni) {
                red[(wl * 64 + ni * 16 + l15) * 3 + 0] = pd[ni];
                red[(wl * 64 + ni * 16 + l15) * 3 + 1] = pu[ni];
            }
        }
    }
    __syncthreads();                             // B4: partials in red

    // final reduce + y + scatter
    if (tid < 64) {
        int row = tid;
        float d = 0.f, su = 0.f, sv = 0.f;
        #pragma unroll
        for (int cg = 0; cg < 8; ++cg) {
            d  += red[(cg * 64 + row) * 3 + 0];
            su += red[(cg * 64 + row) * 3 + 1];
            sv += red[(cg * 64 + row) * 3 + 2];
        }
        float un = fmaxf(sqrtf(su), CEPS);
        float vn = fmaxf(sqrtf(sv), CEPS);
        int grow = row0 + row;
        float yv = d / (un * vn) - logf(sw[grow]);
        for (int j = 0; j < nn1; ++j) {
            int idx = grow - j;
            if (idx < 0) idx += B;
            out[idx * nn1 + j] = yv;
        }
    }
}

extern "C" void kernel_launch(void* const* d_in, const int* in_sizes, int n_in,
                              void* d_out, int out_size, void* d_ws, size_t ws_size,
                              hipStream_t stream)
{
    const int*   user_ids   = (const int*)  d_in[0];
    const int*   item_ids   = (const int*)  d_in[1];
    const float* sw         = (const float*)d_in[2];
    const float* user_table = (const float*)d_in[3];
    const float* item_table = (const float*)d_in[4];
    const float* uW1        = (const float*)d_in[5];
    const float* ub1        = (const float*)d_in[6];
    const float* uW2        = (const float*)d_in[7];
    const float* ub2        = (const float*)d_in[8];
    const float* iW1        = (const float*)d_in[9];
    const float* ib1        = (const float*)d_in[10];
    const float* iW2        = (const float*)d_in[11];
    const float* ib2        = (const float*)d_in[12];

    const int B   = in_sizes[2];       // 16384
    const int nn1 = out_size / B;      // n_neg + 1

    unsigned short* wp   = (unsigned short*)d_ws;
    unsigned short* uW1p = wp;               // 131072
    unsigned short* uW2p = wp + 131072;      // 32768
    unsigned short* iW1p = wp + 163840;      // 65536
    unsigned short* iW2p = wp + 229376;      // 32768
    float* out = (float*)d_out;

    pack_all<<<128, 256, 0, stream>>>(uW1, uW2, iW1, iW2,
                                      uW1p, uW2p, iW1p, iW2p);
    fused_sbc<<<B / 64, 1024, 0, stream>>>(user_ids, item_ids,
                                           user_table, item_table,
                                           uW1p, ub1, uW2p, ub2,
                                           iW1p, ib1, iW2p, ib2,
                                           sw, out, B, nn1);
}

// Round 8
// 28.301 us; speedup vs baseline: 8.4550x; 1.0092x over previous
//
#include <hip/hip_runtime.h>
#include <math.h>

#define CEPS 1e-8f

typedef __attribute__((ext_vector_type(8))) short bf16x8;
typedef __attribute__((ext_vector_type(4))) float f32x4;
typedef __attribute__((ext_vector_type(4))) unsigned int u32x4;
typedef __attribute__((ext_vector_type(2))) unsigned int u32x2;

__device__ __forceinline__ unsigned short f2bf(float f) {
    unsigned u = __builtin_bit_cast(unsigned, f);
    u += 0x7fffu + ((u >> 16) & 1u);            // round-nearest-even
    return (unsigned short)(u >> 16);
}

// Pack weights fp32 -> bf16, MFMA fragment layout [K/8][N][8].
__global__ __launch_bounds__(256)
void pack_all(const float* __restrict__ uW1, const float* __restrict__ uW2,
              const float* __restrict__ iW1, const float* __restrict__ iW2,
              unsigned short* __restrict__ o1, unsigned short* __restrict__ o2,
              unsigned short* __restrict__ o3, unsigned short* __restrict__ o4)
{
    int g = blockIdx.x * 256 + threadIdx.x;     // 32768 entries
    const float* src; unsigned short* dst; int N; int base;
    if (g < 16384)      { src = uW1; dst = o1; N = 256; base = 0;     }
    else if (g < 20480) { src = uW2; dst = o2; N = 128; base = 16384; }
    else if (g < 28672) { src = iW1; dst = o3; N = 256; base = 20480; }
    else                { src = iW2; dst = o4; N = 128; base = 28672; }
    int i = g - base;
    int kg = i / N, n = i - kg * N;
    unsigned short tmp[8];
    #pragma unroll
    for (int j = 0; j < 8; ++j)
        tmp[j] = f2bf(src[(kg * 8 + j) * N + n]);
    *reinterpret_cast<bf16x8*>(dst + ((size_t)i << 3)) =
        *reinterpret_cast<bf16x8*>(tmp);
}

// ---- fused towers, 32 rows/block, 512 threads (8 waves), 2 blocks/CU ----
// Waves 0-3: user tower.  Waves 4-7: item tower (concurrent).
// Swapped-operand MFMA: D[wcol][erow] = mfma(Wfrag, efrag).

template<int F>
__device__ __forceinline__ void stage_emb(const int* __restrict__ ids,
                                          const float* __restrict__ table,
                                          unsigned short* e_s, int row0, int tid)
{
    constexpr int FC = F * 8;                    // 16B chunks per row
    constexpr int IT = (32 * FC) / 512;
    int idv[IT];
    #pragma unroll
    for (int it = 0; it < IT; ++it) {
        int c = tid + it * 512;
        int r = c / FC, f = (c % FC) >> 3;
        idv[it] = ids[(row0 + r) * F + f];
    }
    #pragma unroll
    for (int it = 0; it < IT; ++it) {
        int c = tid + it * 512;
        int r = c / FC, rem = c % FC;
        const float* src = table + (size_t)idv[it] * 64 + (rem & 7) * 8;
        float4 aa = *reinterpret_cast<const float4*>(src);
        float4 bb = *reinterpret_cast<const float4*>(src + 4);
        u32x4 pk;
        pk.x = f2bf(aa.x) | ((unsigned)f2bf(aa.y) << 16);
        pk.y = f2bf(aa.z) | ((unsigned)f2bf(aa.w) << 16);
        pk.z = f2bf(bb.x) | ((unsigned)f2bf(bb.y) << 16);
        pk.w = f2bf(bb.z) | ((unsigned)f2bf(bb.w) << 16);
        int byte = r * (F * 128) + rem * 16;
        byte ^= (r & 7) << 4;
        *reinterpret_cast<u32x4*>(reinterpret_cast<char*>(e_s) + byte) = pk;
    }
}

// LDS fragment read: 8 K-contiguous bf16 of row (ni*16+l15) at k-slice l4.
template<int KB>
__device__ __forceinline__ bf16x8 loadA(const unsigned short* s, int ks, int ni,
                                        int l15, int l4)
{
    int row = ni * 16 + l15;
    int byte = row * (KB * 2) + ks * 64 + l4 * 16;
    byte ^= (row & 7) << 4;
    return *reinterpret_cast<const bf16x8*>(
               reinterpret_cast<const char*>(s) + byte);
}

// GEMM1 (swapped): wave owns w-cols [wl*64, +64) (4 frags), 32 e-rows (2 frags).
template<int K1>
__device__ __forceinline__ void gemm1(
    const unsigned short* e_s, unsigned short* h_s,
    const unsigned short* __restrict__ W1p, const float* __restrict__ b1,
    int l15, int l4, int wl, const bf16x8* w0)
{
    constexpr int NKS = K1 / 32;
    f32x4 acc[4][2];
    #pragma unroll
    for (int mi = 0; mi < 4; ++mi)
        #pragma unroll
        for (int ni = 0; ni < 2; ++ni) acc[mi][ni] = (f32x4){0.f, 0.f, 0.f, 0.f};

    const unsigned short* Wbase = W1p + ((l4 * 256 + wl * 64 + l15) << 3);
    bf16x8 wf[3][4], ef[2][2];
    #pragma unroll
    for (int mi = 0; mi < 4; ++mi) {
        wf[0][mi] = w0[mi];
        wf[1][mi] = *reinterpret_cast<const bf16x8*>(Wbase + 8192 + (mi << 7));
    }
    #pragma unroll
    for (int ni = 0; ni < 2; ++ni) ef[0][ni] = loadA<K1>(e_s, 0, ni, l15, l4);

    #pragma unroll
    for (int ks = 0; ks < NKS; ++ks) {
        if (ks + 2 < NKS) {
            #pragma unroll
            for (int mi = 0; mi < 4; ++mi)
                wf[(ks + 2) % 3][mi] = *reinterpret_cast<const bf16x8*>(
                    Wbase + (ks + 2) * 8192 + (mi << 7));
        }
        if (ks + 1 < NKS) {
            #pragma unroll
            for (int ni = 0; ni < 2; ++ni)
                ef[(ks + 1) & 1][ni] = loadA<K1>(e_s, ks + 1, ni, l15, l4);
        }
        __builtin_amdgcn_s_setprio(1);
        #pragma unroll
        for (int mi = 0; mi < 4; ++mi)
            #pragma unroll
            for (int ni = 0; ni < 2; ++ni)
                acc[mi][ni] = __builtin_amdgcn_mfma_f32_16x16x32_bf16(
                                  wf[ks % 3][mi], ef[ks & 1][ni], acc[mi][ni], 0, 0, 0);
        __builtin_amdgcn_s_setprio(0);
    }
    // epilogue: bias + relu; lane holds 4 consecutive w-cols of one row -> b64
    #pragma unroll
    for (int mi = 0; mi < 4; ++mi) {
        const float4 bb = *reinterpret_cast<const float4*>(
                              &b1[wl * 64 + mi * 16 + l4 * 4]);
        #pragma unroll
        for (int ni = 0; ni < 2; ++ni) {
            float v0 = acc[mi][ni][0] + bb.x; v0 = v0 > 0.f ? v0 : 0.f;
            float v1 = acc[mi][ni][1] + bb.y; v1 = v1 > 0.f ? v1 : 0.f;
            float v2 = acc[mi][ni][2] + bb.z; v2 = v2 > 0.f ? v2 : 0.f;
            float v3 = acc[mi][ni][3] + bb.w; v3 = v3 > 0.f ? v3 : 0.f;
            u32x2 d;
            d.x = f2bf(v0) | ((unsigned)f2bf(v1) << 16);
            d.y = f2bf(v2) | ((unsigned)f2bf(v3) << 16);
            int row = ni * 16 + l15;
            int w0c = wl * 64 + mi * 16 + l4 * 4;
            int byte = (row * 256 + w0c) * 2;
            byte ^= (row & 7) << 4;
            *reinterpret_cast<u32x2*>(reinterpret_cast<char*>(h_s) + byte) = d;
        }
    }
}

// GEMM2 (swapped): wave owns out-cols [wl*32, +32) (2 frags), 32 rows (2 frags).
__device__ __forceinline__ void gemm2(
    const unsigned short* h_s, const unsigned short* __restrict__ W2p,
    f32x4 (&acc)[2][2], int l15, int l4, int wl, const bf16x8* w0)
{
    #pragma unroll
    for (int mi = 0; mi < 2; ++mi)
        #pragma unroll
        for (int ni = 0; ni < 2; ++ni) acc[mi][ni] = (f32x4){0.f, 0.f, 0.f, 0.f};

    const unsigned short* Wbase = W2p + ((l4 * 128 + wl * 32 + l15) << 3);
    bf16x8 wf[3][2], hf[2][2];
    #pragma unroll
    for (int mi = 0; mi < 2; ++mi) {
        wf[0][mi] = w0[mi];
        wf[1][mi] = *reinterpret_cast<const bf16x8*>(Wbase + 4096 + (mi << 7));
    }
    #pragma unroll
    for (int ni = 0; ni < 2; ++ni) hf[0][ni] = loadA<256>(h_s, 0, ni, l15, l4);

    #pragma unroll
    for (int ks = 0; ks < 8; ++ks) {
        if (ks + 2 < 8) {
            #pragma unroll
            for (int mi = 0; mi < 2; ++mi)
                wf[(ks + 2) % 3][mi] = *reinterpret_cast<const bf16x8*>(
                    Wbase + (ks + 2) * 4096 + (mi << 7));
        }
        if (ks + 1 < 8) {
            #pragma unroll
            for (int ni = 0; ni < 2; ++ni)
                hf[(ks + 1) & 1][ni] = loadA<256>(h_s, ks + 1, ni, l15, l4);
        }
        __builtin_amdgcn_s_setprio(1);
        #pragma unroll
        for (int mi = 0; mi < 2; ++mi)
            #pragma unroll
            for (int ni = 0; ni < 2; ++ni)
                acc[mi][ni] = __builtin_amdgcn_mfma_f32_16x16x32_bf16(
                                  wf[ks % 3][mi], hf[ks & 1][ni], acc[mi][ni], 0, 0, 0);
        __builtin_amdgcn_s_setprio(0);
    }
}

__global__ __launch_bounds__(512, 4)
void fused_sbc(const int* __restrict__ user_ids,  const int* __restrict__ item_ids,
               const float* __restrict__ user_table, const float* __restrict__ item_table,
               const unsigned short* __restrict__ uW1p, const float* __restrict__ ub1,
               const unsigned short* __restrict__ uW2p, const float* __restrict__ ub2,
               const unsigned short* __restrict__ iW1p, const float* __restrict__ ib1,
               const unsigned short* __restrict__ iW2p, const float* __restrict__ ib2,
               const float* __restrict__ sw, float* __restrict__ out,
               int B, int nn1)
{
    __shared__ __align__(16) unsigned short smem[40960];   // 80 KB -> 2 blk/CU
    unsigned short* e_u = smem;                  // [32][512]  32 KB
    unsigned short* e_i = smem + 16384;          // [32][256]  16 KB
    unsigned short* h_u = smem + 24576;          // [32][256]  16 KB
    unsigned short* h_i = smem + 32768;          // [32][256]  16 KB
    float* V_lds = reinterpret_cast<float*>(smem);          // [32][132] over e_u
    float* red   = reinterpret_cast<float*>(smem + 16384);  // [4][32][3] over e_i

    const int tid  = threadIdx.x;
    const int lane = tid & 63;
    const int w    = tid >> 6;
    const int l15  = lane & 15, l4 = lane >> 4;
    const int role = w >> 2;                     // 0 = user, 1 = item
    const int wl   = w & 3;
    const int row0 = blockIdx.x * 32;

    const unsigned short* W1sel = role ? iW1p : uW1p;
    const unsigned short* W2sel = role ? iW2p : uW2p;

    // preload ks=0 GEMM1 weight fragments (in flight across staging + barrier)
    bf16x8 w0g1[4];
    {
        const unsigned short* base = W1sel + ((l4 * 256 + wl * 64 + l15) << 3);
        #pragma unroll
        for (int mi = 0; mi < 4; ++mi)
            w0g1[mi] = *reinterpret_cast<const bf16x8*>(base + (mi << 7));
    }
    stage_emb<8>(user_ids, user_table, e_u, row0, tid);
    stage_emb<4>(item_ids, item_table, e_i, row0, tid);
    __syncthreads();                             // B1: embeddings staged

    if (role == 0) gemm1<512>(e_u, h_u, uW1p, ub1, l15, l4, wl, w0g1);
    else           gemm1<256>(e_i, h_i, iW1p, ib1, l15, l4, wl, w0g1);
    bf16x8 w0g2[2];
    {
        const unsigned short* base = W2sel + ((l4 * 128 + wl * 32 + l15) << 3);
        w0g2[0] = *reinterpret_cast<const bf16x8*>(base);
        w0g2[1] = *reinterpret_cast<const bf16x8*>(base + 128);
    }
    __syncthreads();                             // B2: h_u, h_i ready

    f32x4 acc2[2][2];
    if (role == 0) gemm2(h_u, uW2p, acc2, l15, l4, wl, w0g2);
    else           gemm2(h_i, iW2p, acc2, l15, l4, wl, w0g2);

    // item waves: relu(V) -> V_lds + ||v||^2 partials
    if (role == 1) {
        float pv[2] = {0.f, 0.f};
        #pragma unroll
        for (int mi = 0; mi < 2; ++mi) {
            const int colb = wl * 32 + mi * 16 + l4 * 4;
            const float4 bv = *reinterpret_cast<const float4*>(&ib2[colb]);
            #pragma unroll
            for (int ni = 0; ni < 2; ++ni) {
                int row = ni * 16 + l15;
                float v0 = acc2[mi][ni][0] + bv.x; v0 = v0 > 0.f ? v0 : 0.f;
                float v1 = acc2[mi][ni][1] + bv.y; v1 = v1 > 0.f ? v1 : 0.f;
                float v2 = acc2[mi][ni][2] + bv.z; v2 = v2 > 0.f ? v2 : 0.f;
                float v3 = acc2[mi][ni][3] + bv.w; v3 = v3 > 0.f ? v3 : 0.f;
                float4 vv = {v0, v1, v2, v3};
                *reinterpret_cast<float4*>(&V_lds[row * 132 + colb]) = vv;
                pv[ni] += v0 * v0 + v1 * v1 + v2 * v2 + v3 * v3;
            }
        }
        #pragma unroll
        for (int ni = 0; ni < 2; ++ni) {
            pv[ni] += __shfl_xor(pv[ni], 16);
            pv[ni] += __shfl_xor(pv[ni], 32);
        }
        if (l4 == 0) {
            #pragma unroll
            for (int ni = 0; ni < 2; ++ni)
                red[(wl * 32 + ni * 16 + l15) * 3 + 2] = pv[ni];
        }
    }
    __syncthreads();                             // B3: V published

    // user waves: relu(U), dot + ||u||^2 partials
    if (role == 0) {
        float pd[2] = {0.f, 0.f}, pu[2] = {0.f, 0.f};
        #pragma unroll
        for (int mi = 0; mi < 2; ++mi) {
            const int colb = wl * 32 + mi * 16 + l4 * 4;
            const float4 bu = *reinterpret_cast<const float4*>(&ub2[colb]);
            #pragma unroll
            for (int ni = 0; ni < 2; ++ni) {
                int row = ni * 16 + l15;
                float u0 = acc2[mi][ni][0] + bu.x; u0 = u0 > 0.f ? u0 : 0.f;
                float u1 = acc2[mi][ni][1] + bu.y; u1 = u1 > 0.f ? u1 : 0.f;
                float u2 = acc2[mi][ni][2] + bu.z; u2 = u2 > 0.f ? u2 : 0.f;
                float u3 = acc2[mi][ni][3] + bu.w; u3 = u3 > 0.f ? u3 : 0.f;
                const float4 vv = *reinterpret_cast<const float4*>(
                                      &V_lds[row * 132 + colb]);
                pd[ni] += u0 * vv.x + u1 * vv.y + u2 * vv.z + u3 * vv.w;
                pu[ni] += u0 * u0 + u1 * u1 + u2 * u2 + u3 * u3;
            }
        }
        #pragma unroll
        for (int ni = 0; ni < 2; ++ni) {
            pd[ni] += __shfl_xor(pd[ni], 16);
            pd[ni] += __shfl_xor(pd[ni], 32);
            pu[ni] += __shfl_xor(pu[ni], 16);
            pu[ni] += __shfl_xor(pu[ni], 32);
        }
        if (l4 == 0) {
            #pragma unroll
            for (int ni = 0; ni < 2; ++ni) {
                red[(wl * 32 + ni * 16 + l15) * 3 + 0] = pd[ni];
                red[(wl * 32 + ni * 16 + l15) * 3 + 1] = pu[ni];
            }
        }
    }
    __syncthreads();                             // B4: partials in red

    // final reduce + y + scatter
    if (tid < 32) {
        int row = tid;
        float d = 0.f, su = 0.f, sv = 0.f;
        #pragma unroll
        for (int cg = 0; cg < 4; ++cg) {
            d  += red[(cg * 32 + row) * 3 + 0];
            su += red[(cg * 32 + row) * 3 + 1];
            sv += red[(cg * 32 + row) * 3 + 2];
        }
        float un = fmaxf(sqrtf(su), CEPS);
        float vn = fmaxf(sqrtf(sv), CEPS);
        int grow = row0 + row;
        float yv = d / (un * vn) - logf(sw[grow]);
        for (int j = 0; j < nn1; ++j) {
            int idx = grow - j;
            if (idx < 0) idx += B;
            out[idx * nn1 + j] = yv;
        }
    }
}

extern "C" void kernel_launch(void* const* d_in, const int* in_sizes, int n_in,
                              void* d_out, int out_size, void* d_ws, size_t ws_size,
                              hipStream_t stream)
{
    const int*   user_ids   = (const int*)  d_in[0];
    const int*   item_ids   = (const int*)  d_in[1];
    const float* sw         = (const float*)d_in[2];
    const float* user_table = (const float*)d_in[3];
    const float* item_table = (const float*)d_in[4];
    const float* uW1        = (const float*)d_in[5];
    const float* ub1        = (const float*)d_in[6];
    const float* uW2        = (const float*)d_in[7];
    const float* ub2        = (const float*)d_in[8];
    const float* iW1        = (const float*)d_in[9];
    const float* ib1        = (const float*)d_in[10];
    const float* iW2        = (const float*)d_in[11];
    const float* ib2        = (const float*)d_in[12];

    const int B   = in_sizes[2];       // 16384
    const int nn1 = out_size / B;      // n_neg + 1

    unsigned short* wp   = (unsigned short*)d_ws;
    unsigned short* uW1p = wp;               // 131072
    unsigned short* uW2p = wp + 131072;      // 32768
    unsigned short* iW1p = wp + 163840;      // 65536
    unsigned short* iW2p = wp + 229376;      // 32768
    float* out = (float*)d_out;

    pack_all<<<128, 256, 0, stream>>>(uW1, uW2, iW1, iW2,
                                      uW1p, uW2p, iW1p, iW2p);
    fused_sbc<<<B / 32, 512, 0, stream>>>(user_ids, item_ids,
                                          user_table, item_table,
                                          uW1p, ub1, uW2p, ub2,
                                          iW1p, ib1, iW2p, ib2,
                                          sw, out, B, nn1);
}